// Round 1
// baseline (283.807 us; speedup 1.0000x reference)
//
#include <hip/hip_runtime.h>
#include <hip/hip_bf16.h>
#include <math.h>

// Problem constants
constexpr int Nimg = 4;
constexpr int Cin  = 256;
constexpr int Hc   = 64;
constexpr int Wc   = 64;
constexpr int HWc  = Hc * Wc;          // 4096
constexpr int Mrows = Nimg * HWc;      // 16384
constexpr int Gg   = 16;
constexpr int Cgc  = Cin / Gg;         // 16
constexpr int K2c  = 9;
constexpr int OMC  = Gg * K2c * 3;     // 432
constexpr int C2c  = 256;
constexpr float EPSc = 1e-5f;

// ---------------------------------------------------------------------------
// Generic fp32 tiled GEMM: C[M x Nn] = A[M x K] @ B[K x Nn] + bias
// A_FROM_X: A is the NCHW tensor x, logically A[m][k] = x[n][k][h][w]
//           (m = n*HW + h*W + w), i.e. gather with stride HW between k.
// Tile 128x128, BK=16, 256 threads, 8x8 micro-tile.
// ---------------------------------------------------------------------------
template<bool A_FROM_X>
__global__ __launch_bounds__(256) void gemm128(
    const float* __restrict__ A, const float* __restrict__ Bw,
    const float* __restrict__ bias, float* __restrict__ Cout,
    int M, int K, int Nn)
{
    __shared__ float As[16][128];
    __shared__ float Bs[16][128];
    const int tid  = threadIdx.x;
    const int row0 = blockIdx.y * 128;
    const int col0 = blockIdx.x * 128;
    const int tx = tid & 15;   // col group
    const int ty = tid >> 4;   // row group

    float acc[8][8];
#pragma unroll
    for (int i = 0; i < 8; i++)
#pragma unroll
        for (int j = 0; j < 8; j++) acc[i][j] = 0.f;

    for (int k0 = 0; k0 < K; k0 += 16) {
        // ---- load A tile (128 rows x 16 k) ----
        if constexpr (A_FROM_X) {
            const int n  = row0 >> 12;      // 4096 pixels per image, tiles aligned
            const int p0 = row0 & 4095;
            const int ar = tid & 127;
            const int kq = tid >> 7;        // 0..1
            const float* xb = A + (size_t)n * Cin * HWc + p0 + ar;
#pragma unroll
            for (int i = 0; i < 8; i++) {
                const int k = kq * 8 + i;
                As[k][ar] = xb[(size_t)(k0 + k) * HWc];
            }
        } else {
            const int kv = tid & 3;         // which float4 in k
            const int am = tid >> 2;        // 0..63
#pragma unroll
            for (int half = 0; half < 2; half++) {
                const int r = am + half * 64;
                const float4 f = *reinterpret_cast<const float4*>(
                    A + (size_t)(row0 + r) * K + k0 + kv * 4);
                As[kv * 4 + 0][r] = f.x;
                As[kv * 4 + 1][r] = f.y;
                As[kv * 4 + 2][r] = f.z;
                As[kv * 4 + 3][r] = f.w;
            }
        }
        // ---- load B tile (16 k x 128 cols), zero-fill OOB cols ----
        {
            const int jc = tid & 127;
            const int kq = tid >> 7;
            const int col = col0 + jc;
#pragma unroll
            for (int i = 0; i < 8; i++) {
                const int k = kq * 8 + i;
                Bs[k][jc] = (col < Nn) ? Bw[(size_t)(k0 + k) * Nn + col] : 0.f;
            }
        }
        __syncthreads();
        // ---- compute ----
#pragma unroll
        for (int kk = 0; kk < 16; kk++) {
            float a_[8], b_[8];
#pragma unroll
            for (int i = 0; i < 8; i++) a_[i] = As[kk][ty * 8 + i];
#pragma unroll
            for (int j = 0; j < 8; j++) b_[j] = Bs[kk][tx * 8 + j];
#pragma unroll
            for (int i = 0; i < 8; i++)
#pragma unroll
                for (int j = 0; j < 8; j++)
                    acc[i][j] += a_[i] * b_[j];
        }
        __syncthreads();
    }
    // ---- epilogue: add bias, store ----
#pragma unroll
    for (int i = 0; i < 8; i++) {
        const int r = row0 + ty * 8 + i;
#pragma unroll
        for (int j = 0; j < 8; j++) {
            const int cidx = col0 + tx * 8 + j;
            if (cidx < Nn)
                Cout[(size_t)r * Nn + cidx] = acc[i][j] + bias[cidx];
        }
    }
}

// ---------------------------------------------------------------------------
// Deformable sampling. One thread per (pixel m, group g); 16 channels in regs.
// out[m][g*16+c] = sum_k sum_corner w_corner * valid * mask * v[m', g*16+c]
// ---------------------------------------------------------------------------
__global__ __launch_bounds__(256) void dcn_sample(
    const float* __restrict__ v, const float* __restrict__ om,
    float* __restrict__ sampled)
{
    const int tid = threadIdx.x;
    const int g  = tid & 15;
    const int pl = tid >> 4;
    const int m  = blockIdx.x * 16 + pl;
    const int n  = m >> 12;
    const int p  = m & 4095;
    const int h  = p >> 6;
    const int w  = p & 63;

    const float* omr = om + (size_t)m * OMC + g * 27;
    float offv[18];
#pragma unroll
    for (int i = 0; i < 18; i++) offv[i] = omr[i];
    float maskv[9];
#pragma unroll
    for (int k = 0; k < 9; k++) maskv[k] = omr[18 + k];

    float acc[16];
#pragma unroll
    for (int c = 0; c < 16; c++) acc[c] = 0.f;

    const float* vb = v + (size_t)n * HWc * Cin + g * 16;

#pragma unroll
    for (int k = 0; k < 9; k++) {
        const float sy = (float)h + (float)(k / 3 - 1) + offv[2 * k];
        const float sx = (float)w + (float)(k % 3 - 1) + offv[2 * k + 1];
        const float y0f = floorf(sy), x0f = floorf(sx);
        const float fy = sy - y0f, fx = sx - x0f;
        const int y0 = (int)y0f, x0 = (int)x0f;
        const float mk = maskv[k];
#pragma unroll
        for (int cy = 0; cy < 2; cy++) {
            const int yy = y0 + cy;
            if (yy < 0 || yy >= Hc) continue;
            const float wy = cy ? fy : 1.f - fy;
#pragma unroll
            for (int cx = 0; cx < 2; cx++) {
                const int xx = x0 + cx;
                if (xx < 0 || xx >= Wc) continue;
                const float wx = cx ? fx : 1.f - fx;
                const float wk = wy * wx * mk;
                const float4* v4 = reinterpret_cast<const float4*>(
                    vb + (size_t)(yy * Wc + xx) * Cin);
#pragma unroll
                for (int q = 0; q < 4; q++) {
                    const float4 t = v4[q];
                    acc[q * 4 + 0] += wk * t.x;
                    acc[q * 4 + 1] += wk * t.y;
                    acc[q * 4 + 2] += wk * t.z;
                    acc[q * 4 + 3] += wk * t.w;
                }
            }
        }
    }
    float4* outp = reinterpret_cast<float4*>(sampled + (size_t)m * Cin + g * 16);
#pragma unroll
    for (int q = 0; q < 4; q++)
        outp[q] = make_float4(acc[q * 4 + 0], acc[q * 4 + 1],
                              acc[q * 4 + 2], acc[q * 4 + 3]);
}

// ---------------------------------------------------------------------------
// Per-channel partial sums over 64-row stripes (deterministic, no atomics)
// ---------------------------------------------------------------------------
__global__ __launch_bounds__(256) void stats1(
    const float* __restrict__ o, float* __restrict__ psum,
    float* __restrict__ psumsq)
{
    const int t = threadIdx.x;
    const int b = blockIdx.x;   // 0..255
    float s = 0.f, s2 = 0.f;
    const float* op = o + (size_t)b * 64 * C2c + t;
#pragma unroll 4
    for (int r = 0; r < 64; r++) {
        const float x = op[(size_t)r * C2c];
        s += x; s2 += x * x;
    }
    psum[b * C2c + t]  = s;
    psumsq[b * C2c + t] = s2;
}

__global__ __launch_bounds__(256) void stats2(
    const float* __restrict__ psum, const float* __restrict__ psumsq,
    float* __restrict__ meanp, float* __restrict__ rsigp)
{
    const int t = threadIdx.x;   // 256 threads, 1 block
    float s = 0.f, s2 = 0.f;
    for (int b = 0; b < 256; b++) {
        s  += psum[b * C2c + t];
        s2 += psumsq[b * C2c + t];
    }
    const float inv = 1.f / (float)Mrows;
    const float mean = s * inv;
    const float var  = s2 * inv - mean * mean;
    meanp[t] = mean;
    rsigp[t] = rsqrtf(var + EPSc);
}

// ---------------------------------------------------------------------------
// Normalize + SiLU + NHWC->NCHW transpose. 64 pixels x 64 channels per block.
// ---------------------------------------------------------------------------
__global__ __launch_bounds__(256) void norm_silu_transpose(
    const float* __restrict__ o, const float* __restrict__ meanp,
    const float* __restrict__ rsigp, const float* __restrict__ gamma,
    const float* __restrict__ beta, float* __restrict__ out)
{
    __shared__ float tile[64][65];
    const int tid = threadIdx.x;
    const int p0 = blockIdx.x * 64;   // pixel tile within image
    const int c0 = blockIdx.y * 64;   // channel tile
    const int n  = blockIdx.z;
    const int m0 = n * HWc + p0;
    {
        const int lc = tid & 63, lr4 = tid >> 6;
#pragma unroll
        for (int i = 0; i < 16; i++) {
            const int r = lr4 * 16 + i;
            tile[r][lc] = o[(size_t)(m0 + r) * C2c + c0 + lc];
        }
    }
    __syncthreads();
    {
        const int lp = tid & 63, lcq = tid >> 6;
#pragma unroll
        for (int i = 0; i < 16; i++) {
            const int c  = lcq * 16 + i;
            const int ch = c0 + c;
            const float x = tile[lp][c];
            const float y = gamma[ch] * (x - meanp[ch]) * rsigp[ch] + beta[ch];
            const float sy = y / (1.f + expf(-y));
            out[(size_t)n * C2c * HWc + (size_t)ch * HWc + p0 + lp] = sy;
        }
    }
}

// ---------------------------------------------------------------------------
extern "C" void kernel_launch(void* const* d_in, const int* in_sizes, int n_in,
                              void* d_out, int out_size, void* d_ws, size_t ws_size,
                              hipStream_t stream)
{
    const float* x     = (const float*)d_in[0];
    const float* Wv    = (const float*)d_in[1];
    const float* bv    = (const float*)d_in[2];
    const float* Wom   = (const float*)d_in[3];
    const float* bom   = (const float*)d_in[4];
    const float* Wout  = (const float*)d_in[5];
    const float* bout  = (const float*)d_in[6];
    const float* gamma = (const float*)d_in[7];
    const float* beta  = (const float*)d_in[8];
    float* out = (float*)d_out;

    float* ws      = (float*)d_ws;
    float* v       = ws;                      // 16384*256  = 4,194,304
    float* om      = v + (size_t)Mrows * Cin; // 16384*432  = 7,077,888
    float* sampled = om + (size_t)Mrows * OMC;
    float* o       = sampled + (size_t)Mrows * Cin;
    float* psum    = o + (size_t)Mrows * C2c; // 256*256
    float* psumsq  = psum + 256 * 256;
    float* meanp   = psumsq + 256 * 256;
    float* rsigp   = meanp + 256;

    // v = xl @ Wv + bv        (M=16384, K=256, N=256)
    gemm128<true><<<dim3(2, 128), 256, 0, stream>>>(x, Wv, bv, v, Mrows, Cin, Cin);
    // om = xl @ Wom + bom     (N=432)
    gemm128<true><<<dim3(4, 128), 256, 0, stream>>>(x, Wom, bom, om, Mrows, Cin, OMC);
    // deformable sampling
    dcn_sample<<<Mrows / 16, 256, 0, stream>>>(v, om, sampled);
    // o = sampled @ Wout + bout
    gemm128<false><<<dim3(2, 128), 256, 0, stream>>>(sampled, Wout, bout, o, Mrows, Cin, C2c);
    // channel stats (deterministic two-pass)
    stats1<<<256, 256, 0, stream>>>(o, psum, psumsq);
    stats2<<<1, 256, 0, stream>>>(psum, psumsq, meanp, rsigp);
    // normalize + SiLU + transpose to NCHW
    norm_silu_transpose<<<dim3(64, 4, 4), 256, 0, stream>>>(o, meanp, rsigp, gamma, beta, out);
}

// Round 2
// 122.293 us; speedup vs baseline: 2.3207x; 2.3207x over previous
//
#include <hip/hip_runtime.h>
#include <hip/hip_bf16.h>
#include <math.h>

// Problem constants
constexpr int Nimg = 4;
constexpr int Cin  = 256;
constexpr int Hc   = 64;
constexpr int Wc   = 64;
constexpr int HWc  = Hc * Wc;          // 4096
constexpr int Mrows = Nimg * HWc;      // 16384
constexpr int Gg   = 16;
constexpr int K2c  = 9;
constexpr int OMC  = Gg * K2c * 3;     // 432
constexpr int OMCpad = 512;
constexpr int C2c  = 256;
constexpr float EPSc = 1e-5f;

typedef __attribute__((ext_vector_type(8))) short short8v;   // 8 bf16 bits
typedef __attribute__((ext_vector_type(4))) float f32x4;

__device__ __forceinline__ unsigned short f2bf(float f) {
    return __builtin_bit_cast(unsigned short, __float2bfloat16(f));
}

__device__ __forceinline__ void gload16(const unsigned short* g, unsigned short* l) {
    __builtin_amdgcn_global_load_lds(
        (const __attribute__((address_space(1))) void*)g,
        (__attribute__((address_space(3))) void*)l, 16, 0, 0);
}

// ---------------------------------------------------------------------------
// x (NCHW fp32) -> A[m][k] bf16 (m = n*HW + p, k = channel). 64px x 64ch tiles.
// ---------------------------------------------------------------------------
__global__ __launch_bounds__(256) void convert_x(
    const float* __restrict__ x, unsigned short* __restrict__ A)
{
    __shared__ float tile[64][65];
    const int t  = threadIdx.x;
    const int p0 = blockIdx.x * 64;
    const int c0 = blockIdx.y * 64;
    const int n  = blockIdx.z;
    const float* xb = x + ((size_t)n * Cin + c0) * HWc + p0;
#pragma unroll
    for (int i = 0; i < 16; i++) {
        const int c = i * 4 + (t >> 6);
        tile[c][t & 63] = xb[(size_t)c * HWc + (t & 63)];
    }
    __syncthreads();
    unsigned short* Ab = A + ((size_t)(n * HWc) + p0) * Cin + c0;
#pragma unroll
    for (int i = 0; i < 8; i++) {
        const int p  = i * 8 + (t >> 5);
        const int c2 = (t & 31) * 2;
        const unsigned lo = f2bf(tile[c2][p]);
        const unsigned hi = f2bf(tile[c2 + 1][p]);
        *(unsigned*)(Ab + (size_t)p * Cin + c2) = lo | (hi << 16);
    }
}

// ---------------------------------------------------------------------------
// Weights fp32 [K][N] -> transposed bf16 [Npad][K], zero-padded columns.
// ---------------------------------------------------------------------------
__global__ __launch_bounds__(256) void convert_w(
    const float* __restrict__ Wv, const float* __restrict__ Wom,
    const float* __restrict__ Wout,
    unsigned short* __restrict__ WvT, unsigned short* __restrict__ WomT,
    unsigned short* __restrict__ WoutT)
{
    const int t = threadIdx.x;
    const int seg = blockIdx.y;
    const int e = blockIdx.x * 256 + t;
    const float* src; unsigned short* dst; int N; int total;
    if (seg == 0)      { src = Wv;   dst = WvT;   N = 256; total = 256 * 256; }
    else if (seg == 1) { src = Wom;  dst = WomT;  N = 432; total = 512 * 256; }
    else               { src = Wout; dst = WoutT; N = 256; total = 256 * 256; }
    if (e >= total) return;
    const int nc = e >> 8, k = e & 255;
    const float val = (nc < N) ? src[(size_t)k * N + nc] : 0.f;
    dst[e] = f2bf(val);
}

// ---------------------------------------------------------------------------
// bf16 MFMA GEMM: C[M x Nreal] = A[M x 256] @ Bt[Npad x 256]^T + bias
// 128x128 tile, BK=32, 4 waves (2x2), 64x64 per wave, 16x16x32 MFMA.
// LDS staged via global_load_lds width 16 (linear layout).
// ---------------------------------------------------------------------------
__global__ __launch_bounds__(256) void gemm_mfma(
    const unsigned short* __restrict__ A,
    const unsigned short* __restrict__ Bt,
    const float* __restrict__ bias,
    float* __restrict__ C, int ldc, int Nreal)
{
    __shared__ unsigned short As[128 * 32];
    __shared__ unsigned short Bs[128 * 32];
    const int t    = threadIdx.x;
    const int lane = t & 63;
    const int wr   = (t >> 7);            // wave row (0..1)
    const int wc   = (t >> 6) & 1;        // wave col (0..1)
    const int row0 = blockIdx.y * 128;
    const int col0 = blockIdx.x * 128;

    f32x4 acc[4][4];
#pragma unroll
    for (int m = 0; m < 4; m++)
#pragma unroll
        for (int n = 0; n < 4; n++) acc[m][n] = (f32x4)0.f;

    // staging: round i in {0,1}; thread t covers row r=(i*256+t)>>2, k off (t&3)*8
    const int r0   = t >> 2;
    const int koff = (t & 3) * 8;
    const unsigned short* gA = A  + (size_t)(row0 + r0) * 256 + koff;
    const unsigned short* gB = Bt + (size_t)(col0 + r0) * 256 + koff;
    const int wbase = (t & 192) * 8;      // wave-uniform LDS elem base (round 0)

    const int aoff = ((wr * 64) + (lane & 15)) * 32 + (lane >> 4) * 8;
    const int boff = ((wc * 64) + (lane & 15)) * 32 + (lane >> 4) * 8;

    for (int k0 = 0; k0 < 256; k0 += 32) {
        gload16(gA + k0,             As + wbase);
        gload16(gA + k0 + 64 * 256,  As + 2048 + wbase);
        gload16(gB + k0,             Bs + wbase);
        gload16(gB + k0 + 64 * 256,  Bs + 2048 + wbase);
        __syncthreads();

        short8v a_[4], b_[4];
#pragma unroll
        for (int m = 0; m < 4; m++)
            a_[m] = *(const short8v*)(As + aoff + m * 16 * 32);
#pragma unroll
        for (int n = 0; n < 4; n++)
            b_[n] = *(const short8v*)(Bs + boff + n * 16 * 32);
#pragma unroll
        for (int m = 0; m < 4; m++)
#pragma unroll
            for (int n = 0; n < 4; n++)
                acc[m][n] = __builtin_amdgcn_mfma_f32_16x16x32_bf16(
                    a_[m], b_[n], acc[m][n], 0, 0, 0);
        __syncthreads();
    }

    // epilogue: D row=(lane>>4)*4+r, col=lane&15 within each 16x16 fragment
    const int rbase = row0 + wr * 64 + ((lane >> 4) << 2);
    const int cbase = col0 + wc * 64 + (lane & 15);
#pragma unroll
    for (int n = 0; n < 4; n++) {
        const int col = cbase + n * 16;
        if (col >= Nreal) continue;
        const float bb = bias[col];
#pragma unroll
        for (int m = 0; m < 4; m++) {
#pragma unroll
            for (int r = 0; r < 4; r++) {
                C[(size_t)(rbase + m * 16 + r) * ldc + col] = acc[m][n][r] + bb;
            }
        }
    }
}

// ---------------------------------------------------------------------------
// Deformable sampling. One thread per (pixel m, group g); 16 channels in regs.
// Emits bf16 (feeds GEMM3's A operand directly).
// ---------------------------------------------------------------------------
__global__ __launch_bounds__(256) void dcn_sample(
    const float* __restrict__ v, const float* __restrict__ om,
    unsigned short* __restrict__ sampled)
{
    const int tid = threadIdx.x;
    const int g  = tid & 15;
    const int pl = tid >> 4;
    const int m  = blockIdx.x * 16 + pl;
    const int n  = m >> 12;
    const int p  = m & 4095;
    const int h  = p >> 6;
    const int w  = p & 63;

    const float* omr = om + (size_t)m * OMC + g * 27;
    float offv[18];
#pragma unroll
    for (int i = 0; i < 18; i++) offv[i] = omr[i];
    float maskv[9];
#pragma unroll
    for (int k = 0; k < 9; k++) maskv[k] = omr[18 + k];

    float acc[16];
#pragma unroll
    for (int c = 0; c < 16; c++) acc[c] = 0.f;

    const float* vb = v + (size_t)n * HWc * Cin + g * 16;

#pragma unroll
    for (int k = 0; k < 9; k++) {
        const float sy = (float)h + (float)(k / 3 - 1) + offv[2 * k];
        const float sx = (float)w + (float)(k % 3 - 1) + offv[2 * k + 1];
        const float y0f = floorf(sy), x0f = floorf(sx);
        const float fy = sy - y0f, fx = sx - x0f;
        const int y0 = (int)y0f, x0 = (int)x0f;
        const float mk = maskv[k];
#pragma unroll
        for (int cy = 0; cy < 2; cy++) {
            const int yy = y0 + cy;
            if (yy < 0 || yy >= Hc) continue;
            const float wy = cy ? fy : 1.f - fy;
#pragma unroll
            for (int cx = 0; cx < 2; cx++) {
                const int xx = x0 + cx;
                if (xx < 0 || xx >= Wc) continue;
                const float wx = cx ? fx : 1.f - fx;
                const float wk = wy * wx * mk;
                const float4* v4 = reinterpret_cast<const float4*>(
                    vb + (size_t)(yy * Wc + xx) * Cin);
#pragma unroll
                for (int q = 0; q < 4; q++) {
                    const float4 tv = v4[q];
                    acc[q * 4 + 0] += wk * tv.x;
                    acc[q * 4 + 1] += wk * tv.y;
                    acc[q * 4 + 2] += wk * tv.z;
                    acc[q * 4 + 3] += wk * tv.w;
                }
            }
        }
    }
    unsigned pk[8];
#pragma unroll
    for (int j = 0; j < 8; j++)
        pk[j] = (unsigned)f2bf(acc[2 * j]) | ((unsigned)f2bf(acc[2 * j + 1]) << 16);
    uint4* dst = reinterpret_cast<uint4*>(sampled + (size_t)m * Cin + g * 16);
    dst[0] = make_uint4(pk[0], pk[1], pk[2], pk[3]);
    dst[1] = make_uint4(pk[4], pk[5], pk[6], pk[7]);
}

// ---------------------------------------------------------------------------
// Per-channel partial sums over 64-row stripes (deterministic, no atomics)
// ---------------------------------------------------------------------------
__global__ __launch_bounds__(256) void stats1(
    const float* __restrict__ o, float* __restrict__ psum,
    float* __restrict__ psumsq)
{
    const int t = threadIdx.x;
    const int b = blockIdx.x;   // 0..255
    float s = 0.f, s2 = 0.f;
    const float* op = o + (size_t)b * 64 * C2c + t;
#pragma unroll 4
    for (int r = 0; r < 64; r++) {
        const float x = op[(size_t)r * C2c];
        s += x; s2 += x * x;
    }
    psum[b * C2c + t]   = s;
    psumsq[b * C2c + t] = s2;
}

__global__ __launch_bounds__(256) void stats2(
    const float* __restrict__ psum, const float* __restrict__ psumsq,
    float* __restrict__ meanp, float* __restrict__ rsigp)
{
    const int t = threadIdx.x;   // 256 threads, 1 block
    float s = 0.f, s2 = 0.f;
    for (int b = 0; b < 256; b++) {
        s  += psum[b * C2c + t];
        s2 += psumsq[b * C2c + t];
    }
    const float inv = 1.f / (float)Mrows;
    const float mean = s * inv;
    const float var  = s2 * inv - mean * mean;
    meanp[t] = mean;
    rsigp[t] = rsqrtf(var + EPSc);
}

// ---------------------------------------------------------------------------
// Normalize + SiLU + NHWC->NCHW transpose. 64 pixels x 64 channels per block.
// ---------------------------------------------------------------------------
__global__ __launch_bounds__(256) void norm_silu_transpose(
    const float* __restrict__ o, const float* __restrict__ meanp,
    const float* __restrict__ rsigp, const float* __restrict__ gamma,
    const float* __restrict__ beta, float* __restrict__ out)
{
    __shared__ float tile[64][65];
    const int tid = threadIdx.x;
    const int p0 = blockIdx.x * 64;
    const int c0 = blockIdx.y * 64;
    const int n  = blockIdx.z;
    const int m0 = n * HWc + p0;
    {
        const int lc = tid & 63, lr4 = tid >> 6;
#pragma unroll
        for (int i = 0; i < 16; i++) {
            const int r = lr4 * 16 + i;
            tile[r][lc] = o[(size_t)(m0 + r) * C2c + c0 + lc];
        }
    }
    __syncthreads();
    {
        const int lp = tid & 63, lcq = tid >> 6;
#pragma unroll
        for (int i = 0; i < 16; i++) {
            const int c  = lcq * 16 + i;
            const int ch = c0 + c;
            const float x = tile[lp][c];
            const float y = gamma[ch] * (x - meanp[ch]) * rsigp[ch] + beta[ch];
            const float sy = y / (1.f + expf(-y));
            out[(size_t)n * C2c * HWc + (size_t)ch * HWc + p0 + lp] = sy;
        }
    }
}

// ---------------------------------------------------------------------------
extern "C" void kernel_launch(void* const* d_in, const int* in_sizes, int n_in,
                              void* d_out, int out_size, void* d_ws, size_t ws_size,
                              hipStream_t stream)
{
    const float* x     = (const float*)d_in[0];
    const float* Wv    = (const float*)d_in[1];
    const float* bv    = (const float*)d_in[2];
    const float* Wom   = (const float*)d_in[3];
    const float* bom   = (const float*)d_in[4];
    const float* Wout  = (const float*)d_in[5];
    const float* bout  = (const float*)d_in[6];
    const float* gamma = (const float*)d_in[7];
    const float* beta  = (const float*)d_in[8];
    float* out = (float*)d_out;

    float* ws = (float*)d_ws;
    unsigned short* Ax = (unsigned short*)ws;                 // 4,194,304 bf16 = 2,097,152 f
    float* v      = ws + 2097152;                             // 4,194,304 f
    float* om     = v + 4194304;                              // 7,077,888 f
    unsigned short* samp = (unsigned short*)(om + 7077888);   // 4,194,304 bf16
    float* o      = v;                                        // alias: v dead after sampling
    float* psum   = om + 7077888 + 2097152;
    float* psumsq = psum + 65536;
    float* meanp  = psumsq + 65536;
    float* rsigp  = meanp + 256;
    unsigned short* WvT   = (unsigned short*)(rsigp + 256);   // 65,536 bf16
    unsigned short* WomT  = WvT + 65536;                      // 131,072 bf16 (padded)
    unsigned short* WoutT = WomT + 131072;                    // 65,536 bf16

    // prep: bf16 conversions
    convert_x<<<dim3(64, 4, 4), 256, 0, stream>>>(x, Ax);
    convert_w<<<dim3(512, 3), 256, 0, stream>>>(Wv, Wom, Wout, WvT, WomT, WoutT);
    // v = xl @ Wv + bv
    gemm_mfma<<<dim3(2, 128), 256, 0, stream>>>(Ax, WvT, bv, v, 256, 256);
    // om = xl @ Wom + bom
    gemm_mfma<<<dim3(4, 128), 256, 0, stream>>>(Ax, WomT, bom, om, 432, 432);
    // deformable sampling -> bf16
    dcn_sample<<<Mrows / 16, 256, 0, stream>>>(v, om, samp);
    // o = sampled @ Wout + bout   (o aliases v; v no longer needed)
    gemm_mfma<<<dim3(2, 128), 256, 0, stream>>>(samp, WoutT, bout, o, 256, 256);
    // channel stats (deterministic two-pass)
    stats1<<<256, 256, 0, stream>>>(o, psum, psumsq);
    stats2<<<1, 256, 0, stream>>>(psum, psumsq, meanp, rsigp);
    // normalize + SiLU + transpose to NCHW
    norm_silu_transpose<<<dim3(64, 4, 4), 256, 0, stream>>>(o, meanp, rsigp, gamma, beta, out);
}

// Round 3
// 102.726 us; speedup vs baseline: 2.7628x; 1.1905x over previous
//
#include <hip/hip_runtime.h>
#include <hip/hip_bf16.h>
#include <math.h>

// Problem constants
constexpr int Nimg = 4;
constexpr int Cin  = 256;
constexpr int Hc   = 64;
constexpr int Wc   = 64;
constexpr int HWc  = Hc * Wc;          // 4096
constexpr int Mrows = Nimg * HWc;      // 16384
constexpr int Gg   = 16;
constexpr int K2c  = 9;
constexpr int OMC  = Gg * K2c * 3;     // 432
constexpr int C2c  = 256;
constexpr float EPSc = 1e-5f;

typedef __attribute__((ext_vector_type(8))) short short8v;   // 8 bf16 bits
typedef __attribute__((ext_vector_type(4))) float f32x4;

__device__ __forceinline__ unsigned short f2bf(float f) {
    return __builtin_bit_cast(unsigned short, __float2bfloat16(f));
}

__device__ __forceinline__ void gload16(const unsigned short* g, unsigned short* l) {
    __builtin_amdgcn_global_load_lds(
        (const __attribute__((address_space(1))) void*)g,
        (__attribute__((address_space(3))) void*)l, 16, 0, 0);
}

// ---------------------------------------------------------------------------
// x (NCHW fp32) -> A[m][k] bf16 (m = n*HW + p, k = channel). 64px x 64ch tiles.
// ---------------------------------------------------------------------------
__global__ __launch_bounds__(256) void convert_x(
    const float* __restrict__ x, unsigned short* __restrict__ A)
{
    __shared__ float tile[64][65];
    const int t  = threadIdx.x;
    const int p0 = blockIdx.x * 64;
    const int c0 = blockIdx.y * 64;
    const int n  = blockIdx.z;
    const float* xb = x + ((size_t)n * Cin + c0) * HWc + p0;
#pragma unroll
    for (int i = 0; i < 16; i++) {
        const int c = i * 4 + (t >> 6);
        tile[c][t & 63] = xb[(size_t)c * HWc + (t & 63)];
    }
    __syncthreads();
    unsigned short* Ab = A + ((size_t)(n * HWc) + p0) * Cin + c0;
#pragma unroll
    for (int i = 0; i < 8; i++) {
        const int p  = i * 8 + (t >> 5);
        const int c2 = (t & 31) * 2;
        const unsigned lo = f2bf(tile[c2][p]);
        const unsigned hi = f2bf(tile[c2 + 1][p]);
        *(unsigned*)(Ab + (size_t)p * Cin + c2) = lo | (hi << 16);
    }
}

// ---------------------------------------------------------------------------
// Weights fp32 [K][N] -> transposed bf16 [Npad][K], zero-padded columns.
// ---------------------------------------------------------------------------
__global__ __launch_bounds__(256) void convert_w(
    const float* __restrict__ Wv, const float* __restrict__ Wom,
    const float* __restrict__ Wout,
    unsigned short* __restrict__ WvT, unsigned short* __restrict__ WomT,
    unsigned short* __restrict__ WoutT)
{
    const int t = threadIdx.x;
    const int seg = blockIdx.y;
    const int e = blockIdx.x * 256 + t;
    const float* src; unsigned short* dst; int N; int total;
    if (seg == 0)      { src = Wv;   dst = WvT;   N = 256; total = 256 * 256; }
    else if (seg == 1) { src = Wom;  dst = WomT;  N = 432; total = 512 * 256; }
    else               { src = Wout; dst = WoutT; N = 256; total = 256 * 256; }
    if (e >= total) return;
    const int nc = e >> 8, k = e & 255;
    const float val = (nc < N) ? src[(size_t)k * N + nc] : 0.f;
    dst[e] = f2bf(val);
}

// ---------------------------------------------------------------------------
// bf16 MFMA GEMM: C[M x Nreal] = A[M x 256] @ Bt[Npad x 256]^T + bias
// 128x128 tile, BK=32, 4 waves (2x2), 64x64 per wave, 16x16x32 MFMA.
// ---------------------------------------------------------------------------
__global__ __launch_bounds__(256) void gemm_mfma(
    const unsigned short* __restrict__ A,
    const unsigned short* __restrict__ Bt,
    const float* __restrict__ bias,
    float* __restrict__ C, int ldc, int Nreal)
{
    __shared__ unsigned short As[128 * 32];
    __shared__ unsigned short Bs[128 * 32];
    const int t    = threadIdx.x;
    const int lane = t & 63;
    const int wr   = (t >> 7);            // wave row (0..1)
    const int wc   = (t >> 6) & 1;        // wave col (0..1)
    const int row0 = blockIdx.y * 128;
    const int col0 = blockIdx.x * 128;

    f32x4 acc[4][4];
#pragma unroll
    for (int m = 0; m < 4; m++)
#pragma unroll
        for (int n = 0; n < 4; n++) acc[m][n] = (f32x4)0.f;

    const int r0   = t >> 2;
    const int koff = (t & 3) * 8;
    const unsigned short* gA = A  + (size_t)(row0 + r0) * 256 + koff;
    const unsigned short* gB = Bt + (size_t)(col0 + r0) * 256 + koff;
    const int wbase = (t & 192) * 8;      // wave-uniform LDS elem base

    const int aoff = ((wr * 64) + (lane & 15)) * 32 + (lane >> 4) * 8;
    const int boff = ((wc * 64) + (lane & 15)) * 32 + (lane >> 4) * 8;

    for (int k0 = 0; k0 < 256; k0 += 32) {
        gload16(gA + k0,             As + wbase);
        gload16(gA + k0 + 64 * 256,  As + 2048 + wbase);
        gload16(gB + k0,             Bs + wbase);
        gload16(gB + k0 + 64 * 256,  Bs + 2048 + wbase);
        __syncthreads();

        short8v a_[4], b_[4];
#pragma unroll
        for (int m = 0; m < 4; m++)
            a_[m] = *(const short8v*)(As + aoff + m * 16 * 32);
#pragma unroll
        for (int n = 0; n < 4; n++)
            b_[n] = *(const short8v*)(Bs + boff + n * 16 * 32);
#pragma unroll
        for (int m = 0; m < 4; m++)
#pragma unroll
            for (int n = 0; n < 4; n++)
                acc[m][n] = __builtin_amdgcn_mfma_f32_16x16x32_bf16(
                    a_[m], b_[n], acc[m][n], 0, 0, 0);
        __syncthreads();
    }

    const int rbase = row0 + wr * 64 + ((lane >> 4) << 2);
    const int cbase = col0 + wc * 64 + (lane & 15);
#pragma unroll
    for (int n = 0; n < 4; n++) {
        const int col = cbase + n * 16;
        if (col >= Nreal) continue;
        const float bb = bias[col];
#pragma unroll
        for (int m = 0; m < 4; m++) {
#pragma unroll
            for (int r = 0; r < 4; r++) {
                C[(size_t)(rbase + m * 16 + r) * ldc + col] = acc[m][n][r] + bb;
            }
        }
    }
}

// ---------------------------------------------------------------------------
// Deformable sampling, cooperative 4-lane teams.
// Block: 4 pixels x 16 groups x 4 lanes. Lane owns 4 channels (float4).
// om staged in LDS (broadcast reads). Branchless corners (clamped addr,
// zeroed weight) -> all 36 team-coalesced 64B loads can batch.
// ---------------------------------------------------------------------------
__global__ __launch_bounds__(256) void dcn_sample(
    const float* __restrict__ v, const float* __restrict__ om,
    unsigned short* __restrict__ sampled)
{
    __shared__ float om_s[4 * OMC];   // 1728 floats
    const int t  = threadIdx.x;
    const int m0 = blockIdx.x * 4;

    {   // stage om for the block's 4 pixels (432 float4s)
        const float4* src = reinterpret_cast<const float4*>(om + (size_t)m0 * OMC);
        float4* dst = reinterpret_cast<float4*>(om_s);
        for (int i = t; i < 432; i += 256) dst[i] = src[i];
    }
    __syncthreads();

    const int cl = t & 3;          // channel quad 0..3
    const int g  = (t >> 2) & 15;  // group
    const int pl = t >> 6;         // pixel-local 0..3
    const int m  = m0 + pl;
    const int n  = m >> 12;
    const int p  = m & 4095;
    const int h  = p >> 6;
    const int w  = p & 63;

    const float* omr = om_s + pl * OMC + g * 27;
    const float* vb  = v + ((size_t)n * HWc) * Cin + g * 16 + cl * 4;

    float4 acc = make_float4(0.f, 0.f, 0.f, 0.f);

#pragma unroll
    for (int k = 0; k < 9; k++) {
        const float sy = (float)(h + (k / 3 - 1)) + omr[2 * k];
        const float sx = (float)(w + (k % 3 - 1)) + omr[2 * k + 1];
        const float y0f = floorf(sy), x0f = floorf(sx);
        const float fy = sy - y0f, fx = sx - x0f;
        const int y0 = (int)y0f, x0 = (int)x0f;
        const float mk = omr[18 + k];
#pragma unroll
        for (int cy = 0; cy < 2; cy++) {
            const int yy = y0 + cy;
            const float wy = cy ? fy : 1.f - fy;
            const int yc = min(max(yy, 0), Hc - 1);
            const bool vy = (yy >= 0) & (yy < Hc);
#pragma unroll
            for (int cx = 0; cx < 2; cx++) {
                const int xx = x0 + cx;
                const float wx = cx ? fx : 1.f - fx;
                const int xc = min(max(xx, 0), Wc - 1);
                const bool vx = (xx >= 0) & (xx < Wc);
                const float wk = (vy & vx) ? (wy * wx * mk) : 0.f;
                const float4 tv = *reinterpret_cast<const float4*>(
                    vb + (size_t)(yc * Wc + xc) * Cin);
                acc.x += wk * tv.x;
                acc.y += wk * tv.y;
                acc.z += wk * tv.z;
                acc.w += wk * tv.w;
            }
        }
    }
    const unsigned lo = (unsigned)f2bf(acc.x) | ((unsigned)f2bf(acc.y) << 16);
    const unsigned hi = (unsigned)f2bf(acc.z) | ((unsigned)f2bf(acc.w) << 16);
    *reinterpret_cast<uint2*>(sampled + (size_t)m * Cin + g * 16 + cl * 4)
        = make_uint2(lo, hi);
}

// ---------------------------------------------------------------------------
// Per-channel partial sums over 64-row stripes (deterministic, no atomics)
// ---------------------------------------------------------------------------
__global__ __launch_bounds__(256) void stats1(
    const float* __restrict__ o, float* __restrict__ psum,
    float* __restrict__ psumsq)
{
    const int t = threadIdx.x;
    const int b = blockIdx.x;   // 0..255
    float s = 0.f, s2 = 0.f;
    const float* op = o + (size_t)b * 64 * C2c + t;
#pragma unroll 4
    for (int r = 0; r < 64; r++) {
        const float x = op[(size_t)r * C2c];
        s += x; s2 += x * x;
    }
    psum[b * C2c + t]   = s;
    psumsq[b * C2c + t] = s2;
}

__global__ __launch_bounds__(256) void stats2(
    const float* __restrict__ psum, const float* __restrict__ psumsq,
    float* __restrict__ meanp, float* __restrict__ rsigp)
{
    const int t = threadIdx.x;   // 256 threads, 1 block
    float s0 = 0.f, s1 = 0.f, s2_ = 0.f, s3 = 0.f;
    float q0 = 0.f, q1 = 0.f, q2 = 0.f, q3 = 0.f;
    for (int b = 0; b < 256; b += 4) {
        s0 += psum[(b + 0) * C2c + t];   q0 += psumsq[(b + 0) * C2c + t];
        s1 += psum[(b + 1) * C2c + t];   q1 += psumsq[(b + 1) * C2c + t];
        s2_ += psum[(b + 2) * C2c + t];  q2 += psumsq[(b + 2) * C2c + t];
        s3 += psum[(b + 3) * C2c + t];   q3 += psumsq[(b + 3) * C2c + t];
    }
    const float s = (s0 + s1) + (s2_ + s3);
    const float q = (q0 + q1) + (q2 + q3);
    const float inv = 1.f / (float)Mrows;
    const float mean = s * inv;
    const float var  = q * inv - mean * mean;
    meanp[t] = mean;
    rsigp[t] = rsqrtf(var + EPSc);
}

// ---------------------------------------------------------------------------
// Normalize + SiLU + NHWC->NCHW transpose. 64 pixels x 64 channels per block.
// ---------------------------------------------------------------------------
__global__ __launch_bounds__(256) void norm_silu_transpose(
    const float* __restrict__ o, const float* __restrict__ meanp,
    const float* __restrict__ rsigp, const float* __restrict__ gamma,
    const float* __restrict__ beta, float* __restrict__ out)
{
    __shared__ float tile[64][65];
    const int tid = threadIdx.x;
    const int p0 = blockIdx.x * 64;
    const int c0 = blockIdx.y * 64;
    const int n  = blockIdx.z;
    const int m0 = n * HWc + p0;
    {
        const int lc = tid & 63, lr4 = tid >> 6;
#pragma unroll
        for (int i = 0; i < 16; i++) {
            const int r = lr4 * 16 + i;
            tile[r][lc] = o[(size_t)(m0 + r) * C2c + c0 + lc];
        }
    }
    __syncthreads();
    {
        const int lp = tid & 63, lcq = tid >> 6;
#pragma unroll
        for (int i = 0; i < 16; i++) {
            const int c  = lcq * 16 + i;
            const int ch = c0 + c;
            const float x = tile[lp][c];
            const float y = gamma[ch] * (x - meanp[ch]) * rsigp[ch] + beta[ch];
            const float sy = y / (1.f + expf(-y));
            out[(size_t)n * C2c * HWc + (size_t)ch * HWc + p0 + lp] = sy;
        }
    }
}

// ---------------------------------------------------------------------------
extern "C" void kernel_launch(void* const* d_in, const int* in_sizes, int n_in,
                              void* d_out, int out_size, void* d_ws, size_t ws_size,
                              hipStream_t stream)
{
    const float* x     = (const float*)d_in[0];
    const float* Wv    = (const float*)d_in[1];
    const float* bv    = (const float*)d_in[2];
    const float* Wom   = (const float*)d_in[3];
    const float* bom   = (const float*)d_in[4];
    const float* Wout  = (const float*)d_in[5];
    const float* bout  = (const float*)d_in[6];
    const float* gamma = (const float*)d_in[7];
    const float* beta  = (const float*)d_in[8];
    float* out = (float*)d_out;

    float* ws = (float*)d_ws;
    unsigned short* Ax = (unsigned short*)ws;                 // 4,194,304 bf16
    float* v      = ws + 2097152;                             // 4,194,304 f
    float* om     = v + 4194304;                              // 7,077,888 f
    unsigned short* samp = (unsigned short*)(om + 7077888);   // 4,194,304 bf16
    float* o      = v;                                        // alias: v dead after sampling
    float* psum   = om + 7077888 + 2097152;
    float* psumsq = psum + 65536;
    float* meanp  = psumsq + 65536;
    float* rsigp  = meanp + 256;
    unsigned short* WvT   = (unsigned short*)(rsigp + 256);   // 65,536 bf16
    unsigned short* WomT  = WvT + 65536;                      // 131,072 bf16 (padded)
    unsigned short* WoutT = WomT + 131072;                    // 65,536 bf16

    convert_x<<<dim3(64, 4, 4), 256, 0, stream>>>(x, Ax);
    convert_w<<<dim3(512, 3), 256, 0, stream>>>(Wv, Wom, Wout, WvT, WomT, WoutT);
    gemm_mfma<<<dim3(2, 128), 256, 0, stream>>>(Ax, WvT, bv, v, 256, 256);
    gemm_mfma<<<dim3(4, 128), 256, 0, stream>>>(Ax, WomT, bom, om, 432, 432);
    dcn_sample<<<Mrows / 4, 256, 0, stream>>>(v, om, samp);
    gemm_mfma<<<dim3(2, 128), 256, 0, stream>>>(samp, WoutT, bout, o, 256, 256);
    stats1<<<256, 256, 0, stream>>>(o, psum, psumsq);
    stats2<<<1, 256, 0, stream>>>(psum, psumsq, meanp, rsigp);
    norm_silu_transpose<<<dim3(64, 4, 4), 256, 0, stream>>>(o, meanp, rsigp, gamma, beta, out);
}

// Round 4
// 95.916 us; speedup vs baseline: 2.9589x; 1.0710x over previous
//
#include <hip/hip_runtime.h>
#include <hip/hip_bf16.h>
#include <math.h>

// Problem constants
constexpr int Nimg = 4;
constexpr int Cin  = 256;
constexpr int Hc   = 64;
constexpr int Wc   = 64;
constexpr int HWc  = Hc * Wc;          // 4096
constexpr int Mrows = Nimg * HWc;      // 16384
constexpr int Gg   = 16;
constexpr int K2c  = 9;
constexpr int OMC  = Gg * K2c * 3;     // 432
constexpr int C2c  = 256;
constexpr float EPSc = 1e-5f;

typedef __attribute__((ext_vector_type(8))) short short8v;   // 8 bf16 bits
typedef __attribute__((ext_vector_type(4))) float f32x4;

__device__ __forceinline__ unsigned short f2bf(float f) {
    return __builtin_bit_cast(unsigned short, __float2bfloat16(f));
}
__device__ __forceinline__ float bf2f(unsigned short u) {
    return __builtin_bit_cast(float, (unsigned)u << 16);
}

__device__ __forceinline__ void gload16(const unsigned short* g, unsigned short* l) {
    __builtin_amdgcn_global_load_lds(
        (const __attribute__((address_space(1))) void*)g,
        (__attribute__((address_space(3))) void*)l, 16, 0, 0);
}

// Accumulate 4 bf16 channels (8B at p) with weight wk into acc.
__device__ __forceinline__ void acc4(const unsigned short* p, float wk, float4& a) {
    const uint2 u = *reinterpret_cast<const uint2*>(p);
    a.x += wk * __builtin_bit_cast(float, u.x << 16);
    a.y += wk * __builtin_bit_cast(float, u.x & 0xffff0000u);
    a.z += wk * __builtin_bit_cast(float, u.y << 16);
    a.w += wk * __builtin_bit_cast(float, u.y & 0xffff0000u);
}

// ---------------------------------------------------------------------------
// x (NCHW fp32) -> A[m][k] bf16 (m = n*HW + p, k = channel). 64px x 64ch tiles.
// ---------------------------------------------------------------------------
__global__ __launch_bounds__(256) void convert_x(
    const float* __restrict__ x, unsigned short* __restrict__ A)
{
    __shared__ float tile[64][65];
    const int t  = threadIdx.x;
    const int p0 = blockIdx.x * 64;
    const int c0 = blockIdx.y * 64;
    const int n  = blockIdx.z;
    const float* xb = x + ((size_t)n * Cin + c0) * HWc + p0;
#pragma unroll
    for (int i = 0; i < 16; i++) {
        const int c = i * 4 + (t >> 6);
        tile[c][t & 63] = xb[(size_t)c * HWc + (t & 63)];
    }
    __syncthreads();
    unsigned short* Ab = A + ((size_t)(n * HWc) + p0) * Cin + c0;
#pragma unroll
    for (int i = 0; i < 8; i++) {
        const int p  = i * 8 + (t >> 5);
        const int c2 = (t & 31) * 2;
        const unsigned lo = f2bf(tile[c2][p]);
        const unsigned hi = f2bf(tile[c2 + 1][p]);
        *(unsigned*)(Ab + (size_t)p * Cin + c2) = lo | (hi << 16);
    }
}

// ---------------------------------------------------------------------------
// Weights fp32 [K][N] -> transposed bf16 [Npad][K], zero-padded columns.
// ---------------------------------------------------------------------------
__global__ __launch_bounds__(256) void convert_w(
    const float* __restrict__ Wv, const float* __restrict__ Wom,
    const float* __restrict__ Wout,
    unsigned short* __restrict__ WvT, unsigned short* __restrict__ WomT,
    unsigned short* __restrict__ WoutT)
{
    const int t = threadIdx.x;
    const int seg = blockIdx.y;
    const int e = blockIdx.x * 256 + t;
    const float* src; unsigned short* dst; int N; int total;
    if (seg == 0)      { src = Wv;   dst = WvT;   N = 256; total = 256 * 256; }
    else if (seg == 1) { src = Wom;  dst = WomT;  N = 432; total = 512 * 256; }
    else               { src = Wout; dst = WoutT; N = 256; total = 256 * 256; }
    if (e >= total) return;
    const int nc = e >> 8, k = e & 255;
    const float val = (nc < N) ? src[(size_t)k * N + nc] : 0.f;
    dst[e] = f2bf(val);
}

// ---------------------------------------------------------------------------
// bf16 MFMA GEMM: C[M x Nreal] = A[M x 256] @ Bt[Npad x 256]^T + bias
// 128x128 tile, BK=32, 4 waves (2x2), 64x64 per wave, 16x16x32 MFMA.
// OUT_BF16 selects bf16 vs fp32 output.
// ---------------------------------------------------------------------------
template<bool OUT_BF16>
__global__ __launch_bounds__(256) void gemm_mfma(
    const unsigned short* __restrict__ A,
    const unsigned short* __restrict__ Bt,
    const float* __restrict__ bias,
    void* __restrict__ Cv, int ldc, int Nreal)
{
    __shared__ unsigned short As[128 * 32];
    __shared__ unsigned short Bs[128 * 32];
    const int t    = threadIdx.x;
    const int lane = t & 63;
    const int wr   = (t >> 7);
    const int wc   = (t >> 6) & 1;
    const int row0 = blockIdx.y * 128;
    const int col0 = blockIdx.x * 128;

    f32x4 acc[4][4];
#pragma unroll
    for (int m = 0; m < 4; m++)
#pragma unroll
        for (int n = 0; n < 4; n++) acc[m][n] = (f32x4)0.f;

    const int r0   = t >> 2;
    const int koff = (t & 3) * 8;
    const unsigned short* gA = A  + (size_t)(row0 + r0) * 256 + koff;
    const unsigned short* gB = Bt + (size_t)(col0 + r0) * 256 + koff;
    const int wbase = (t & 192) * 8;

    const int aoff = ((wr * 64) + (lane & 15)) * 32 + (lane >> 4) * 8;
    const int boff = ((wc * 64) + (lane & 15)) * 32 + (lane >> 4) * 8;

    for (int k0 = 0; k0 < 256; k0 += 32) {
        gload16(gA + k0,             As + wbase);
        gload16(gA + k0 + 64 * 256,  As + 2048 + wbase);
        gload16(gB + k0,             Bs + wbase);
        gload16(gB + k0 + 64 * 256,  Bs + 2048 + wbase);
        __syncthreads();

        short8v a_[4], b_[4];
#pragma unroll
        for (int m = 0; m < 4; m++)
            a_[m] = *(const short8v*)(As + aoff + m * 16 * 32);
#pragma unroll
        for (int n = 0; n < 4; n++)
            b_[n] = *(const short8v*)(Bs + boff + n * 16 * 32);
#pragma unroll
        for (int m = 0; m < 4; m++)
#pragma unroll
            for (int n = 0; n < 4; n++)
                acc[m][n] = __builtin_amdgcn_mfma_f32_16x16x32_bf16(
                    a_[m], b_[n], acc[m][n], 0, 0, 0);
        __syncthreads();
    }

    const int rbase = row0 + wr * 64 + ((lane >> 4) << 2);
    const int cbase = col0 + wc * 64 + (lane & 15);
#pragma unroll
    for (int n = 0; n < 4; n++) {
        const int col = cbase + n * 16;
        if (col >= Nreal) continue;
        const float bb = bias[col];
#pragma unroll
        for (int m = 0; m < 4; m++) {
#pragma unroll
            for (int r = 0; r < 4; r++) {
                const float val = acc[m][n][r] + bb;
                const size_t idx = (size_t)(rbase + m * 16 + r) * ldc + col;
                if constexpr (OUT_BF16)
                    ((unsigned short*)Cv)[idx] = f2bf(val);
                else
                    ((float*)Cv)[idx] = val;
            }
        }
    }
}

// ---------------------------------------------------------------------------
// Deformable sampling, LDS-tiled. One block per 8x8 pixel tile (256 blocks,
// 1/CU). Stages a 12x12 haloed v tile (bf16, 73.7KB) + tile om rows (bf16,
// 55.3KB) in LDS. 512 threads; each wave handles one output pixel per iter:
// lanes = (group g, channel-quad cl) -> corner reads are contiguous 512B
// ds_read_b64 per wave (conflict-free). Out-of-tile samples (rare) fall back
// to predicated global loads.
// ---------------------------------------------------------------------------
__global__ __launch_bounds__(512) void dcn_sample(
    const unsigned short* __restrict__ vbf,    // [n][4096][256] bf16
    const unsigned short* __restrict__ ombf,   // [m][432] bf16
    unsigned short* __restrict__ sampled)      // [m][256] bf16
{
    __shared__ unsigned short v_s[144 * 256];  // 73728 B
    __shared__ unsigned short om_s[64 * OMC];  // 55296 B
    const int t = threadIdx.x;
    const int b = blockIdx.x;
    const int n   = b >> 6;
    const int py0 = ((b >> 3) & 7) * 8;
    const int px0 = (b & 7) * 8;
    const int y0t = py0 - 2, x0t = px0 - 2;

    // ---- stage v tile: 144 slots x 256ch bf16 = 4608 uint4 ----
    {
        uint4* vd = (uint4*)v_s;
        const unsigned short* vn = vbf + ((size_t)n << 12) * 256;
#pragma unroll
        for (int jj = 0; jj < 9; jj++) {
            const int j = jj * 512 + t;
            const int slot = j >> 5, wi = j & 31;
            const int ly = slot / 12, lx = slot - ly * 12;
            const int gy = min(max(y0t + ly, 0), 63);
            const int gx = min(max(x0t + lx, 0), 63);
            vd[j] = *(const uint4*)(vn + (size_t)((gy << 6) + gx) * 256 + wi * 8);
        }
        // ---- stage om: 64 px x 432 bf16 = 3456 uint4 ----
        uint4* od = (uint4*)om_s;
        for (int j = t; j < 3456; j += 512) {
            const int pl = j / 54, wi = j - pl * 54;
            const int m = (n << 12) + ((py0 + (pl >> 3)) << 6) + px0 + (pl & 7);
            od[j] = *(const uint4*)(ombf + (size_t)m * OMC + wi * 8);
        }
    }
    __syncthreads();

    const int lane = t & 63;
    const int wv   = t >> 6;           // wave id 0..7
    const int g    = lane >> 2;
    const int cl   = lane & 3;
    const int choff = g * 16 + cl * 4;

#pragma unroll 1
    for (int i = 0; i < 8; i++) {
        const int pl = wv * 8 + i;
        const int h  = py0 + (pl >> 3);
        const int w  = px0 + (pl & 7);
        const unsigned short* omr = om_s + pl * OMC + g * 27;
        float4 acc = make_float4(0.f, 0.f, 0.f, 0.f);
#pragma unroll
        for (int k = 0; k < 9; k++) {
            const float offy = bf2f(omr[2 * k]);
            const float offx = bf2f(omr[2 * k + 1]);
            const float mk   = bf2f(omr[18 + k]);
            const float sy = (float)(h + k / 3 - 1) + offy;
            const float sx = (float)(w + k % 3 - 1) + offx;
            const float y0f = floorf(sy), x0f = floorf(sx);
            const float fy = sy - y0f, fx = sx - x0f;
            const int y0 = (int)y0f, x0 = (int)x0f;
            const float ay  = ((unsigned)y0 < 64u) ? (1.f - fy) : 0.f;
            const float by  = ((unsigned)(y0 + 1) < 64u) ? fy : 0.f;
            const float axm = (((unsigned)x0 < 64u) ? (1.f - fx) : 0.f) * mk;
            const float bxm = (((unsigned)(x0 + 1) < 64u) ? fx : 0.f) * mk;
            const float w00 = ay * axm, w01 = ay * bxm;
            const float w10 = by * axm, w11 = by * bxm;
            const int ly = y0 - y0t, lx = x0 - x0t;
            if ((unsigned)ly <= 10u && (unsigned)lx <= 10u) {
                const unsigned short* p00 = v_s + ((ly * 12 + lx) * 256 + choff);
                acc4(p00,                 w00, acc);
                acc4(p00 + 256,           w01, acc);
                acc4(p00 + 12 * 256,      w10, acc);
                acc4(p00 + 12 * 256 + 256, w11, acc);
            } else {
                const int yc0 = min(max(y0, 0), 63), yc1 = min(max(y0 + 1, 0), 63);
                const int xc0 = min(max(x0, 0), 63), xc1 = min(max(x0 + 1, 0), 63);
                const unsigned short* vg = vbf + ((size_t)n << 12) * 256 + choff;
                acc4(vg + (size_t)((yc0 << 6) + xc0) * 256, w00, acc);
                acc4(vg + (size_t)((yc0 << 6) + xc1) * 256, w01, acc);
                acc4(vg + (size_t)((yc1 << 6) + xc0) * 256, w10, acc);
                acc4(vg + (size_t)((yc1 << 6) + xc1) * 256, w11, acc);
            }
        }
        const int m = (n << 12) + (h << 6) + w;
        const unsigned lo = (unsigned)f2bf(acc.x) | ((unsigned)f2bf(acc.y) << 16);
        const unsigned hi = (unsigned)f2bf(acc.z) | ((unsigned)f2bf(acc.w) << 16);
        *reinterpret_cast<uint2*>(sampled + (size_t)m * 256 + choff)
            = make_uint2(lo, hi);
    }
}

// ---------------------------------------------------------------------------
// Per-channel partial sums over 64-row stripes (deterministic, no atomics)
// ---------------------------------------------------------------------------
__global__ __launch_bounds__(256) void stats1(
    const float* __restrict__ o, float* __restrict__ psum,
    float* __restrict__ psumsq)
{
    const int t = threadIdx.x;
    const int b = blockIdx.x;   // 0..255
    float s = 0.f, s2 = 0.f;
    const float* op = o + (size_t)b * 64 * C2c + t;
#pragma unroll 4
    for (int r = 0; r < 64; r++) {
        const float x = op[(size_t)r * C2c];
        s += x; s2 += x * x;
    }
    psum[b * C2c + t]   = s;
    psumsq[b * C2c + t] = s2;
}

__global__ __launch_bounds__(256) void stats2(
    const float* __restrict__ psum, const float* __restrict__ psumsq,
    float* __restrict__ meanp, float* __restrict__ rsigp)
{
    const int t = threadIdx.x;
    float s0 = 0.f, s1 = 0.f, s2_ = 0.f, s3 = 0.f;
    float q0 = 0.f, q1 = 0.f, q2 = 0.f, q3 = 0.f;
    for (int b = 0; b < 256; b += 4) {
        s0  += psum[(b + 0) * C2c + t];   q0 += psumsq[(b + 0) * C2c + t];
        s1  += psum[(b + 1) * C2c + t];   q1 += psumsq[(b + 1) * C2c + t];
        s2_ += psum[(b + 2) * C2c + t];   q2 += psumsq[(b + 2) * C2c + t];
        s3  += psum[(b + 3) * C2c + t];   q3 += psumsq[(b + 3) * C2c + t];
    }
    const float s = (s0 + s1) + (s2_ + s3);
    const float q = (q0 + q1) + (q2 + q3);
    const float inv = 1.f / (float)Mrows;
    const float mean = s * inv;
    const float var  = q * inv - mean * mean;
    meanp[t] = mean;
    rsigp[t] = rsqrtf(var + EPSc);
}

// ---------------------------------------------------------------------------
// Normalize + SiLU + NHWC->NCHW transpose. 64 pixels x 64 channels per block.
// ---------------------------------------------------------------------------
__global__ __launch_bounds__(256) void norm_silu_transpose(
    const float* __restrict__ o, const float* __restrict__ meanp,
    const float* __restrict__ rsigp, const float* __restrict__ gamma,
    const float* __restrict__ beta, float* __restrict__ out)
{
    __shared__ float tile[64][65];
    const int tid = threadIdx.x;
    const int p0 = blockIdx.x * 64;
    const int c0 = blockIdx.y * 64;
    const int n  = blockIdx.z;
    const int m0 = n * HWc + p0;
    {
        const int lc = tid & 63, lr4 = tid >> 6;
#pragma unroll
        for (int i = 0; i < 16; i++) {
            const int r = lr4 * 16 + i;
            tile[r][lc] = o[(size_t)(m0 + r) * C2c + c0 + lc];
        }
    }
    __syncthreads();
    {
        const int lp = tid & 63, lcq = tid >> 6;
#pragma unroll
        for (int i = 0; i < 16; i++) {
            const int c  = lcq * 16 + i;
            const int ch = c0 + c;
            const float x = tile[lp][c];
            const float y = gamma[ch] * (x - meanp[ch]) * rsigp[ch] + beta[ch];
            const float sy = y / (1.f + expf(-y));
            out[(size_t)n * C2c * HWc + (size_t)ch * HWc + p0 + lp] = sy;
        }
    }
}

// ---------------------------------------------------------------------------
extern "C" void kernel_launch(void* const* d_in, const int* in_sizes, int n_in,
                              void* d_out, int out_size, void* d_ws, size_t ws_size,
                              hipStream_t stream)
{
    const float* x     = (const float*)d_in[0];
    const float* Wv    = (const float*)d_in[1];
    const float* bv    = (const float*)d_in[2];
    const float* Wom   = (const float*)d_in[3];
    const float* bom   = (const float*)d_in[4];
    const float* Wout  = (const float*)d_in[5];
    const float* bout  = (const float*)d_in[6];
    const float* gamma = (const float*)d_in[7];
    const float* beta  = (const float*)d_in[8];
    float* out = (float*)d_out;

    float* ws = (float*)d_ws;
    unsigned short* Ax   = (unsigned short*)ws;               // 4,194,304 us
    unsigned short* vbf  = Ax + 4194304;                      // 4,194,304 us
    unsigned short* ombf = vbf + 4194304;                     // 7,077,888 us
    unsigned short* samp = ombf + 7077888;                    // 4,194,304 us
    float* o      = (float*)(samp + 4194304);                 // 4,194,304 f
    float* psum   = o + 4194304;
    float* psumsq = psum + 65536;
    float* meanp  = psumsq + 65536;
    float* rsigp  = meanp + 256;
    unsigned short* WvT   = (unsigned short*)(rsigp + 256);   // 65,536 us
    unsigned short* WomT  = WvT + 65536;                      // 131,072 us (padded)
    unsigned short* WoutT = WomT + 131072;                    // 65,536 us

    convert_x<<<dim3(64, 4, 4), 256, 0, stream>>>(x, Ax);
    convert_w<<<dim3(512, 3), 256, 0, stream>>>(Wv, Wom, Wout, WvT, WomT, WoutT);
    // v = xl @ Wv + bv   -> bf16
    gemm_mfma<true><<<dim3(2, 128), 256, 0, stream>>>(Ax, WvT, bv, vbf, 256, 256);
    // om = xl @ Wom + bom -> bf16
    gemm_mfma<true><<<dim3(4, 128), 256, 0, stream>>>(Ax, WomT, bom, ombf, 432, 432);
    // deformable sampling (LDS-tiled) -> bf16
    dcn_sample<<<256, 512, 0, stream>>>(vbf, ombf, samp);
    // o = sampled @ Wout + bout -> fp32
    gemm_mfma<false><<<dim3(2, 128), 256, 0, stream>>>(samp, WoutT, bout, o, 256, 256);
    stats1<<<256, 256, 0, stream>>>(o, psum, psumsq);
    stats2<<<1, 256, 0, stream>>>(psum, psumsq, meanp, rsigp);
    norm_silu_transpose<<<dim3(64, 4, 4), 256, 0, stream>>>(o, meanp, rsigp, gamma, beta, out);
}

// Round 5
// 82.123 us; speedup vs baseline: 3.4559x; 1.1680x over previous
//
#include <hip/hip_runtime.h>
#include <hip/hip_bf16.h>
#include <math.h>

// Problem constants
constexpr int Nimg = 4;
constexpr int Cin  = 256;
constexpr int Hc   = 64;
constexpr int Wc   = 64;
constexpr int HWc  = Hc * Wc;          // 4096
constexpr int Mrows = Nimg * HWc;      // 16384
constexpr int Gg   = 16;
constexpr int K2c  = 9;
constexpr int OMC  = Gg * K2c * 3;     // 432
constexpr int C2c  = 256;
constexpr float EPSc = 1e-5f;

typedef __attribute__((ext_vector_type(8))) short short8v;   // 8 bf16 bits
typedef __attribute__((ext_vector_type(4))) float f32x4;

__device__ __forceinline__ unsigned short f2bf(float f) {
    return __builtin_bit_cast(unsigned short, __float2bfloat16(f));
}
__device__ __forceinline__ float bf2f(unsigned short u) {
    return __builtin_bit_cast(float, (unsigned)u << 16);
}

__device__ __forceinline__ void gload16(const unsigned short* g, unsigned short* l) {
    __builtin_amdgcn_global_load_lds(
        (const __attribute__((address_space(1))) void*)g,
        (__attribute__((address_space(3))) void*)l, 16, 0, 0);
}

// Accumulate 4 bf16 channels (8B at p) with weight wk into acc.
__device__ __forceinline__ void acc4(const unsigned short* p, float wk, float4& a) {
    const uint2 u = *reinterpret_cast<const uint2*>(p);
    a.x += wk * __builtin_bit_cast(float, u.x << 16);
    a.y += wk * __builtin_bit_cast(float, u.x & 0xffff0000u);
    a.z += wk * __builtin_bit_cast(float, u.y << 16);
    a.w += wk * __builtin_bit_cast(float, u.y & 0xffff0000u);
}

// ---------------------------------------------------------------------------
// x (NCHW fp32) -> A[m][k] bf16 (m = n*HW + p, k = channel). 64px x 64ch tiles.
// ---------------------------------------------------------------------------
__global__ __launch_bounds__(256) void convert_x(
    const float* __restrict__ x, unsigned short* __restrict__ A)
{
    __shared__ float tile[64][65];
    const int t  = threadIdx.x;
    const int p0 = blockIdx.x * 64;
    const int c0 = blockIdx.y * 64;
    const int n  = blockIdx.z;
    const float* xb = x + ((size_t)n * Cin + c0) * HWc + p0;
#pragma unroll
    for (int i = 0; i < 16; i++) {
        const int c = i * 4 + (t >> 6);
        tile[c][t & 63] = xb[(size_t)c * HWc + (t & 63)];
    }
    __syncthreads();
    unsigned short* Ab = A + ((size_t)(n * HWc) + p0) * Cin + c0;
#pragma unroll
    for (int i = 0; i < 8; i++) {
        const int p  = i * 8 + (t >> 5);
        const int c2 = (t & 31) * 2;
        const unsigned lo = f2bf(tile[c2][p]);
        const unsigned hi = f2bf(tile[c2 + 1][p]);
        *(unsigned*)(Ab + (size_t)p * Cin + c2) = lo | (hi << 16);
    }
}

// ---------------------------------------------------------------------------
// Weights -> transposed bf16. seg0: WallT rows 0..255 (Wv), seg1: WallT rows
// 256..767 (Wom, zero-pad >=432), seg2: WoutT, seg3: ball (concat bias fp32).
// ---------------------------------------------------------------------------
__global__ __launch_bounds__(256) void convert_w(
    const float* __restrict__ Wv, const float* __restrict__ Wom,
    const float* __restrict__ Wout,
    const float* __restrict__ bv, const float* __restrict__ bom,
    unsigned short* __restrict__ WallT, unsigned short* __restrict__ WoutT,
    float* __restrict__ ball)
{
    const int t = threadIdx.x;
    const int seg = blockIdx.y;
    const int e = blockIdx.x * 256 + t;
    if (seg == 3) {
        if (e < 768)
            ball[e] = (e < 256) ? bv[e] : ((e < 688) ? bom[e - 256] : 0.f);
        return;
    }
    const float* src; unsigned short* dst; int N; int total;
    if (seg == 0)      { src = Wv;   dst = WallT;              N = 256; total = 256 * 256; }
    else if (seg == 1) { src = Wom;  dst = WallT + 256 * 256;  N = 432; total = 512 * 256; }
    else               { src = Wout; dst = WoutT;              N = 256; total = 256 * 256; }
    if (e >= total) return;
    const int nc = e >> 8, k = e & 255;
    const float val = (nc < N) ? src[(size_t)k * N + nc] : 0.f;
    dst[e] = f2bf(val);
}

// ---------------------------------------------------------------------------
// Fused v+om GEMM: [16384 x 768] = A[16384 x 256] @ WallT[768 x 256]^T + ball.
// 128x256 tile, BK=32, 8 waves (2x4), 64x64 per wave. Cols 0..255 -> vbf,
// 256..687 -> ombf (bf16), 688..767 dead pad.
// ---------------------------------------------------------------------------
__global__ __launch_bounds__(512) void gemm_vom(
    const unsigned short* __restrict__ A,
    const unsigned short* __restrict__ Bt,
    const float* __restrict__ ball,
    unsigned short* __restrict__ vbf,
    unsigned short* __restrict__ ombf)
{
    __shared__ unsigned short As[128 * 32];
    __shared__ unsigned short Bs[256 * 32];
    const int t    = threadIdx.x;
    const int lane = t & 63;
    const int wid  = t >> 6;          // 0..7
    const int wr   = wid >> 2;        // 0..1
    const int wc   = wid & 3;         // 0..3
    const int row0 = blockIdx.y * 128;
    const int col0 = blockIdx.x * 256;

    f32x4 acc[4][4];
#pragma unroll
    for (int m = 0; m < 4; m++)
#pragma unroll
        for (int n = 0; n < 4; n++) acc[m][n] = (f32x4)0.f;

    const int r0   = t >> 2;          // 0..127
    const int koff = (t & 3) * 8;
    const unsigned short* gA  = A  + (size_t)(row0 + r0) * 256 + koff;
    const unsigned short* gB0 = Bt + (size_t)(col0 + r0) * 256 + koff;
    const unsigned short* gB1 = Bt + (size_t)(col0 + 128 + r0) * 256 + koff;
    const int sbase = wid * 512;      // wave-uniform LDS elem base (t*8 = sbase + lane*8)

    const int arow = wr * 64 + (lane & 15);
    const int bcol = wc * 64 + (lane & 15);
    const int kq   = (lane >> 4) * 8;

    for (int k0 = 0; k0 < 256; k0 += 32) {
        gload16(gA  + k0, As + sbase);
        gload16(gB0 + k0, Bs + sbase);
        gload16(gB1 + k0, Bs + 4096 + sbase);
        __syncthreads();

        short8v a_[4], b_[4];
#pragma unroll
        for (int m = 0; m < 4; m++)
            a_[m] = *(const short8v*)(As + (arow + m * 16) * 32 + kq);
#pragma unroll
        for (int n = 0; n < 4; n++)
            b_[n] = *(const short8v*)(Bs + (bcol + n * 16) * 32 + kq);
#pragma unroll
        for (int m = 0; m < 4; m++)
#pragma unroll
            for (int n = 0; n < 4; n++)
                acc[m][n] = __builtin_amdgcn_mfma_f32_16x16x32_bf16(
                    a_[m], b_[n], acc[m][n], 0, 0, 0);
        __syncthreads();
    }

    const int rb = row0 + wr * 64 + ((lane >> 4) << 2);
#pragma unroll
    for (int n = 0; n < 4; n++) {
        const int gcol = col0 + wc * 64 + n * 16 + (lane & 15);
        const float bb = ball[gcol];
#pragma unroll
        for (int m = 0; m < 4; m++) {
#pragma unroll
            for (int r = 0; r < 4; r++) {
                const float val = acc[m][n][r] + bb;
                const int row = rb + m * 16 + r;
                if (gcol < 256) {
                    vbf[(size_t)row * 256 + gcol] = f2bf(val);
                } else {
                    const int oc = gcol - 256;
                    if (oc < 432)
                        ombf[(size_t)row * 432 + oc] = f2bf(val);
                }
            }
        }
    }
}

// ---------------------------------------------------------------------------
// Deformable sampling, LDS-tiled (unchanged from round 4).
// ---------------------------------------------------------------------------
__global__ __launch_bounds__(512) void dcn_sample(
    const unsigned short* __restrict__ vbf,
    const unsigned short* __restrict__ ombf,
    unsigned short* __restrict__ sampled)
{
    __shared__ unsigned short v_s[144 * 256];
    __shared__ unsigned short om_s[64 * OMC];
    const int t = threadIdx.x;
    const int b = blockIdx.x;
    const int n   = b >> 6;
    const int py0 = ((b >> 3) & 7) * 8;
    const int px0 = (b & 7) * 8;
    const int y0t = py0 - 2, x0t = px0 - 2;

    {
        uint4* vd = (uint4*)v_s;
        const unsigned short* vn = vbf + ((size_t)n << 12) * 256;
#pragma unroll
        for (int jj = 0; jj < 9; jj++) {
            const int j = jj * 512 + t;
            const int slot = j >> 5, wi = j & 31;
            const int ly = slot / 12, lx = slot - ly * 12;
            const int gy = min(max(y0t + ly, 0), 63);
            const int gx = min(max(x0t + lx, 0), 63);
            vd[j] = *(const uint4*)(vn + (size_t)((gy << 6) + gx) * 256 + wi * 8);
        }
        uint4* od = (uint4*)om_s;
        for (int j = t; j < 3456; j += 512) {
            const int pl = j / 54, wi = j - pl * 54;
            const int m = (n << 12) + ((py0 + (pl >> 3)) << 6) + px0 + (pl & 7);
            od[j] = *(const uint4*)(ombf + (size_t)m * OMC + wi * 8);
        }
    }
    __syncthreads();

    const int lane = t & 63;
    const int wv   = t >> 6;
    const int g    = lane >> 2;
    const int cl   = lane & 3;
    const int choff = g * 16 + cl * 4;

#pragma unroll 1
    for (int i = 0; i < 8; i++) {
        const int pl = wv * 8 + i;
        const int h  = py0 + (pl >> 3);
        const int w  = px0 + (pl & 7);
        const unsigned short* omr = om_s + pl * OMC + g * 27;
        float4 acc = make_float4(0.f, 0.f, 0.f, 0.f);
#pragma unroll
        for (int k = 0; k < 9; k++) {
            const float offy = bf2f(omr[2 * k]);
            const float offx = bf2f(omr[2 * k + 1]);
            const float mk   = bf2f(omr[18 + k]);
            const float sy = (float)(h + k / 3 - 1) + offy;
            const float sx = (float)(w + k % 3 - 1) + offx;
            const float y0f = floorf(sy), x0f = floorf(sx);
            const float fy = sy - y0f, fx = sx - x0f;
            const int y0 = (int)y0f, x0 = (int)x0f;
            const float ay  = ((unsigned)y0 < 64u) ? (1.f - fy) : 0.f;
            const float by  = ((unsigned)(y0 + 1) < 64u) ? fy : 0.f;
            const float axm = (((unsigned)x0 < 64u) ? (1.f - fx) : 0.f) * mk;
            const float bxm = (((unsigned)(x0 + 1) < 64u) ? fx : 0.f) * mk;
            const float w00 = ay * axm, w01 = ay * bxm;
            const float w10 = by * axm, w11 = by * bxm;
            const int ly = y0 - y0t, lx = x0 - x0t;
            if ((unsigned)ly <= 10u && (unsigned)lx <= 10u) {
                const unsigned short* p00 = v_s + ((ly * 12 + lx) * 256 + choff);
                acc4(p00,                  w00, acc);
                acc4(p00 + 256,            w01, acc);
                acc4(p00 + 12 * 256,       w10, acc);
                acc4(p00 + 12 * 256 + 256, w11, acc);
            } else {
                const int yc0 = min(max(y0, 0), 63), yc1 = min(max(y0 + 1, 0), 63);
                const int xc0 = min(max(x0, 0), 63), xc1 = min(max(x0 + 1, 0), 63);
                const unsigned short* vg = vbf + ((size_t)n << 12) * 256 + choff;
                acc4(vg + (size_t)((yc0 << 6) + xc0) * 256, w00, acc);
                acc4(vg + (size_t)((yc0 << 6) + xc1) * 256, w01, acc);
                acc4(vg + (size_t)((yc1 << 6) + xc0) * 256, w10, acc);
                acc4(vg + (size_t)((yc1 << 6) + xc1) * 256, w11, acc);
            }
        }
        const int m = (n << 12) + (h << 6) + w;
        const unsigned lo = (unsigned)f2bf(acc.x) | ((unsigned)f2bf(acc.y) << 16);
        const unsigned hi = (unsigned)f2bf(acc.z) | ((unsigned)f2bf(acc.w) << 16);
        *reinterpret_cast<uint2*>(sampled + (size_t)m * 256 + choff)
            = make_uint2(lo, hi);
    }
}

// ---------------------------------------------------------------------------
// Output GEMM + fused per-block channel stats. o stored bf16; stats from fp32.
// 128x128 tile, BK=32, 4 waves (2x2). psum/psumsq[by][256] per block-row.
// ---------------------------------------------------------------------------
__global__ __launch_bounds__(256) void gemm_out(
    const unsigned short* __restrict__ A,
    const unsigned short* __restrict__ Bt,
    const float* __restrict__ bias,
    unsigned short* __restrict__ obf,
    float* __restrict__ psum, float* __restrict__ psumsq)
{
    __shared__ unsigned short As[128 * 32];
    __shared__ unsigned short Bs[128 * 32];
    __shared__ float ssum[2][128];
    __shared__ float sqsum[2][128];
    const int t    = threadIdx.x;
    const int lane = t & 63;
    const int wr   = (t >> 7);
    const int wc   = (t >> 6) & 1;
    const int row0 = blockIdx.y * 128;
    const int col0 = blockIdx.x * 128;

    f32x4 acc[4][4];
#pragma unroll
    for (int m = 0; m < 4; m++)
#pragma unroll
        for (int n = 0; n < 4; n++) acc[m][n] = (f32x4)0.f;

    const int r0   = t >> 2;
    const int koff = (t & 3) * 8;
    const unsigned short* gA = A  + (size_t)(row0 + r0) * 256 + koff;
    const unsigned short* gB = Bt + (size_t)(col0 + r0) * 256 + koff;
    const int wbase = (t & 192) * 8;

    const int aoff = ((wr * 64) + (lane & 15)) * 32 + (lane >> 4) * 8;
    const int boff = ((wc * 64) + (lane & 15)) * 32 + (lane >> 4) * 8;

    for (int k0 = 0; k0 < 256; k0 += 32) {
        gload16(gA + k0,            As + wbase);
        gload16(gA + k0 + 64 * 256, As + 2048 + wbase);
        gload16(gB + k0,            Bs + wbase);
        gload16(gB + k0 + 64 * 256, Bs + 2048 + wbase);
        __syncthreads();

        short8v a_[4], b_[4];
#pragma unroll
        for (int m = 0; m < 4; m++)
            a_[m] = *(const short8v*)(As + aoff + m * 16 * 32);
#pragma unroll
        for (int n = 0; n < 4; n++)
            b_[n] = *(const short8v*)(Bs + boff + n * 16 * 32);
#pragma unroll
        for (int m = 0; m < 4; m++)
#pragma unroll
            for (int n = 0; n < 4; n++)
                acc[m][n] = __builtin_amdgcn_mfma_f32_16x16x32_bf16(
                    a_[m], b_[n], acc[m][n], 0, 0, 0);
        __syncthreads();
    }

    const int rbase = row0 + wr * 64 + ((lane >> 4) << 2);
    const int cloc  = wc * 64 + (lane & 15);
#pragma unroll
    for (int n = 0; n < 4; n++) {
        const int col = col0 + cloc + n * 16;
        const float bb = bias[col];
        float s = 0.f, q = 0.f;
#pragma unroll
        for (int m = 0; m < 4; m++) {
#pragma unroll
            for (int r = 0; r < 4; r++) {
                const float val = acc[m][n][r] + bb;
                obf[(size_t)(rbase + m * 16 + r) * C2c + col] = f2bf(val);
                s += val; q += val * val;
            }
        }
        // reduce across the 4 row-groups (lane>>4) -> full 64-row column sums
        s += __shfl_xor(s, 16); s += __shfl_xor(s, 32);
        q += __shfl_xor(q, 16); q += __shfl_xor(q, 32);
        if (lane < 16) {
            ssum[wr][cloc + n * 16]  = s;
            sqsum[wr][cloc + n * 16] = q;
        }
    }
    __syncthreads();
    if (t < 128) {
        psum[(size_t)blockIdx.y * 256 + col0 + t]   = ssum[0][t] + ssum[1][t];
        psumsq[(size_t)blockIdx.y * 256 + col0 + t] = sqsum[0][t] + sqsum[1][t];
    }
}

__global__ __launch_bounds__(256) void stats2(
    const float* __restrict__ psum, const float* __restrict__ psumsq,
    float* __restrict__ meanp, float* __restrict__ rsigp)
{
    const int t = threadIdx.x;
    float s0 = 0.f, s1 = 0.f, s2_ = 0.f, s3 = 0.f;
    float q0 = 0.f, q1 = 0.f, q2 = 0.f, q3 = 0.f;
    for (int b = 0; b < 128; b += 4) {
        s0  += psum[(b + 0) * 256 + t];   q0 += psumsq[(b + 0) * 256 + t];
        s1  += psum[(b + 1) * 256 + t];   q1 += psumsq[(b + 1) * 256 + t];
        s2_ += psum[(b + 2) * 256 + t];   q2 += psumsq[(b + 2) * 256 + t];
        s3  += psum[(b + 3) * 256 + t];   q3 += psumsq[(b + 3) * 256 + t];
    }
    const float s = (s0 + s1) + (s2_ + s3);
    const float q = (q0 + q1) + (q2 + q3);
    const float inv = 1.f / (float)Mrows;
    const float mean = s * inv;
    const float var  = q * inv - mean * mean;
    meanp[t] = mean;
    rsigp[t] = rsqrtf(var + EPSc);
}

// ---------------------------------------------------------------------------
// Normalize + SiLU + NHWC->NCHW transpose. o is bf16. 64px x 64ch per block.
// ---------------------------------------------------------------------------
__global__ __launch_bounds__(256) void norm_silu_transpose(
    const unsigned short* __restrict__ obf, const float* __restrict__ meanp,
    const float* __restrict__ rsigp, const float* __restrict__ gamma,
    const float* __restrict__ beta, float* __restrict__ out)
{
    __shared__ float tile[64][65];
    const int tid = threadIdx.x;
    const int p0 = blockIdx.x * 64;
    const int c0 = blockIdx.y * 64;
    const int n  = blockIdx.z;
    const int m0 = n * HWc + p0;
    {
#pragma unroll
        for (int i = 0; i < 8; i++) {
            const int idx = i * 256 + tid;     // 64px x 32 ch-pairs
            const int p  = idx >> 5;
            const int cp = (idx & 31) * 2;
            const unsigned u = *reinterpret_cast<const unsigned*>(
                obf + (size_t)(m0 + p) * C2c + c0 + cp);
            tile[p][cp]     = __builtin_bit_cast(float, u << 16);
            tile[p][cp + 1] = __builtin_bit_cast(float, u & 0xffff0000u);
        }
    }
    __syncthreads();
    {
        const int lp = tid & 63, lcq = tid >> 6;
#pragma unroll
        for (int i = 0; i < 16; i++) {
            const int c  = lcq * 16 + i;
            const int ch = c0 + c;
            const float x = tile[lp][c];
            const float y = gamma[ch] * (x - meanp[ch]) * rsigp[ch] + beta[ch];
            const float sy = y / (1.f + expf(-y));
            out[(size_t)n * C2c * HWc + (size_t)ch * HWc + p0 + lp] = sy;
        }
    }
}

// ---------------------------------------------------------------------------
extern "C" void kernel_launch(void* const* d_in, const int* in_sizes, int n_in,
                              void* d_out, int out_size, void* d_ws, size_t ws_size,
                              hipStream_t stream)
{
    const float* x     = (const float*)d_in[0];
    const float* Wv    = (const float*)d_in[1];
    const float* bv    = (const float*)d_in[2];
    const float* Wom   = (const float*)d_in[3];
    const float* bom   = (const float*)d_in[4];
    const float* Wout  = (const float*)d_in[5];
    const float* bout  = (const float*)d_in[6];
    const float* gamma = (const float*)d_in[7];
    const float* beta  = (const float*)d_in[8];
    float* out = (float*)d_out;

    unsigned short* us = (unsigned short*)d_ws;
    unsigned short* Ax    = us;                    // 4,194,304
    unsigned short* vbf   = Ax + 4194304;          // 4,194,304
    unsigned short* ombf  = vbf + 4194304;         // 7,077,888
    unsigned short* samp  = ombf + 7077888;        // 4,194,304
    unsigned short* obf   = samp + 4194304;        // 4,194,304
    unsigned short* WallT = obf + 4194304;         // 196,608
    unsigned short* WoutT = WallT + 196608;        // 65,536
    float* fs     = (float*)(WoutT + 65536);
    float* psum   = fs;                            // 32,768
    float* psumsq = psum + 32768;                  // 32,768
    float* meanp  = psumsq + 32768;
    float* rsigp  = meanp + 256;
    float* ball   = rsigp + 256;                   // 768

    convert_x<<<dim3(64, 4, 4), 256, 0, stream>>>(x, Ax);
    convert_w<<<dim3(512, 4), 256, 0, stream>>>(Wv, Wom, Wout, bv, bom,
                                                WallT, WoutT, ball);
    // v (cols 0..255) + om (cols 256..687) in one GEMM
    gemm_vom<<<dim3(3, 128), 512, 0, stream>>>(Ax, WallT, ball, vbf, ombf);
    // deformable sampling (LDS-tiled) -> bf16
    dcn_sample<<<256, 512, 0, stream>>>(vbf, ombf, samp);
    // o = sampled @ Wout + bout -> bf16, with fused per-block channel stats
    gemm_out<<<dim3(2, 128), 256, 0, stream>>>(samp, WoutT, bout, obf, psum, psumsq);
    stats2<<<1, 256, 0, stream>>>(psum, psumsq, meanp, rsigp);
    norm_silu_transpose<<<dim3(64, 4, 4), 256, 0, stream>>>(obf, meanp, rsigp,
                                                            gamma, beta, out);
}

// Round 6
// 74.327 us; speedup vs baseline: 3.8184x; 1.1049x over previous
//
#include <hip/hip_runtime.h>
#include <hip/hip_bf16.h>
#include <math.h>

// Problem constants
constexpr int Nimg = 4;
constexpr int Cin  = 256;
constexpr int Hc   = 64;
constexpr int Wc   = 64;
constexpr int HWc  = Hc * Wc;          // 4096
constexpr int Mrows = Nimg * HWc;      // 16384
constexpr int Gg   = 16;
constexpr int K2c  = 9;
constexpr int OMC  = Gg * K2c * 3;     // 432
constexpr int C2c  = 256;
constexpr float EPSc = 1e-5f;

typedef __attribute__((ext_vector_type(8))) short short8v;   // 8 bf16 bits
typedef __attribute__((ext_vector_type(4))) float f32x4;

__device__ __forceinline__ unsigned short f2bf(float f) {
    return __builtin_bit_cast(unsigned short, __float2bfloat16(f));
}
__device__ __forceinline__ float bf2f(unsigned short u) {
    return __builtin_bit_cast(float, (unsigned)u << 16);
}

__device__ __forceinline__ void gload16(const unsigned short* g, unsigned short* l) {
    __builtin_amdgcn_global_load_lds(
        (const __attribute__((address_space(1))) void*)g,
        (__attribute__((address_space(3))) void*)l, 16, 0, 0);
}

// Accumulate 4 bf16 channels (8B at p) with weight wk into acc.
__device__ __forceinline__ void acc4(const unsigned short* p, float wk, float4& a) {
    const uint2 u = *reinterpret_cast<const uint2*>(p);
    a.x += wk * __builtin_bit_cast(float, u.x << 16);
    a.y += wk * __builtin_bit_cast(float, u.x & 0xffff0000u);
    a.z += wk * __builtin_bit_cast(float, u.y << 16);
    a.w += wk * __builtin_bit_cast(float, u.y & 0xffff0000u);
}

// ---------------------------------------------------------------------------
// Fused prep: blocks [0,1024) transpose+convert x (NCHW fp32 -> A[m][k] bf16);
// blocks [1024,2051) convert weights to transposed bf16 + concat bias.
// ---------------------------------------------------------------------------
__global__ __launch_bounds__(256) void prep(
    const float* __restrict__ x,
    const float* __restrict__ Wv, const float* __restrict__ Wom,
    const float* __restrict__ Wout,
    const float* __restrict__ bv, const float* __restrict__ bom,
    unsigned short* __restrict__ A,
    unsigned short* __restrict__ WallT, unsigned short* __restrict__ WoutT,
    float* __restrict__ ball)
{
    __shared__ float tile[64][65];
    const int t   = threadIdx.x;
    const int bid = blockIdx.x;
    if (bid < 1024) {
        const int p0 = (bid & 63) * 64;
        const int c0 = ((bid >> 6) & 3) * 64;
        const int n  = bid >> 8;
        const float* xb = x + ((size_t)n * Cin + c0) * HWc + p0;
#pragma unroll
        for (int i = 0; i < 16; i++) {
            const int c = i * 4 + (t >> 6);
            tile[c][t & 63] = xb[(size_t)c * HWc + (t & 63)];
        }
        __syncthreads();
        unsigned short* Ab = A + ((size_t)(n * HWc) + p0) * Cin + c0;
#pragma unroll
        for (int i = 0; i < 8; i++) {
            const int p  = i * 8 + (t >> 5);
            const int c2 = (t & 31) * 2;
            const unsigned lo = f2bf(tile[c2][p]);
            const unsigned hi = f2bf(tile[c2 + 1][p]);
            *(unsigned*)(Ab + (size_t)p * Cin + c2) = lo | (hi << 16);
        }
        return;
    }
    const int e = (bid - 1024) * 256 + t;
    if (e < 65536) {                       // Wv -> WallT rows 0..255
        const int nc = e >> 8, k = e & 255;
        WallT[e] = f2bf(Wv[(size_t)k * 256 + nc]);
    } else if (e < 196608) {               // Wom -> WallT rows 256..767 (pad)
        const int e2 = e - 65536;
        const int nc = e2 >> 8, k = e2 & 255;
        WallT[e] = f2bf(nc < 432 ? Wom[(size_t)k * 432 + nc] : 0.f);
    } else if (e < 262144) {               // Wout -> WoutT
        const int e3 = e - 196608;
        const int nc = e3 >> 8, k = e3 & 255;
        WoutT[e3] = f2bf(Wout[(size_t)k * 256 + nc]);
    } else if (e < 262912) {               // concat bias
        const int i = e - 262144;
        ball[i] = (i < 256) ? bv[i] : ((i < 688) ? bom[i - 256] : 0.f);
    }
}

// ---------------------------------------------------------------------------
// Fused v+om GEMM: [16384 x 768] = A[16384 x 256] @ WallT[768 x 256]^T + ball.
// 128x256 tile, BK=32, 8 waves (2x4). XCD-swizzled so the 3 col-tiles of one
// row-block land on the same XCD (A-panel L2 reuse).
// ---------------------------------------------------------------------------
__global__ __launch_bounds__(512) void gemm_vom(
    const unsigned short* __restrict__ A,
    const unsigned short* __restrict__ Bt,
    const float* __restrict__ ball,
    unsigned short* __restrict__ vbf,
    unsigned short* __restrict__ ombf)
{
    __shared__ unsigned short As[128 * 32];
    __shared__ unsigned short Bs[256 * 32];
    const int t    = threadIdx.x;
    const int lane = t & 63;
    const int wid  = t >> 6;
    const int wr   = wid >> 2;
    const int wc   = wid & 3;
    // XCD swizzle: vid%8 = XCD; give each XCD 16 row-blocks x 3 col-tiles.
    const int vid = blockIdx.x + 3 * blockIdx.y;
    const int xcd = vid & 7;
    const int j8  = vid >> 3;             // 0..47
    const int row0 = (xcd * 16 + j8 / 3) * 128;
    const int col0 = (j8 % 3) * 256;

    f32x4 acc[4][4];
#pragma unroll
    for (int m = 0; m < 4; m++)
#pragma unroll
        for (int n = 0; n < 4; n++) acc[m][n] = (f32x4)0.f;

    const int r0   = t >> 2;
    const int koff = (t & 3) * 8;
    const unsigned short* gA  = A  + (size_t)(row0 + r0) * 256 + koff;
    const unsigned short* gB0 = Bt + (size_t)(col0 + r0) * 256 + koff;
    const unsigned short* gB1 = Bt + (size_t)(col0 + 128 + r0) * 256 + koff;
    const int sbase = wid * 512;

    const int arow = wr * 64 + (lane & 15);
    const int bcol = wc * 64 + (lane & 15);
    const int kq   = (lane >> 4) * 8;

    for (int k0 = 0; k0 < 256; k0 += 32) {
        gload16(gA  + k0, As + sbase);
        gload16(gB0 + k0, Bs + sbase);
        gload16(gB1 + k0, Bs + 4096 + sbase);
        __syncthreads();

        short8v a_[4], b_[4];
#pragma unroll
        for (int m = 0; m < 4; m++)
            a_[m] = *(const short8v*)(As + (arow + m * 16) * 32 + kq);
#pragma unroll
        for (int n = 0; n < 4; n++)
            b_[n] = *(const short8v*)(Bs + (bcol + n * 16) * 32 + kq);
#pragma unroll
        for (int m = 0; m < 4; m++)
#pragma unroll
            for (int n = 0; n < 4; n++)
                acc[m][n] = __builtin_amdgcn_mfma_f32_16x16x32_bf16(
                    a_[m], b_[n], acc[m][n], 0, 0, 0);
        __syncthreads();
    }

    const int rb = row0 + wr * 64 + ((lane >> 4) << 2);
#pragma unroll
    for (int n = 0; n < 4; n++) {
        const int gcol = col0 + wc * 64 + n * 16 + (lane & 15);
        const float bb = ball[gcol];
#pragma unroll
        for (int m = 0; m < 4; m++) {
#pragma unroll
            for (int r = 0; r < 4; r++) {
                const float val = acc[m][n][r] + bb;
                const int row = rb + m * 16 + r;
                if (gcol < 256) {
                    vbf[(size_t)row * 256 + gcol] = f2bf(val);
                } else {
                    const int oc = gcol - 256;
                    if (oc < 432)
                        ombf[(size_t)row * 432 + oc] = f2bf(val);
                }
            }
        }
    }
}

// ---------------------------------------------------------------------------
// Deformable sampling, LDS-tiled + channel-split. One block per (8x8 px tile,
// 128-ch half): v_s = 144 slots x 128ch bf16 (36.9KB) + om_s = 64px x 8grp x
// 27 bf16 (27.6KB) -> 64.5KB LDS -> 2 blocks/CU. 512 threads, 8 waves; each
// wave-iter covers 2 px x 32 lanes x 4ch. Rare out-of-tile samples fall back
// to predicated global loads.
// ---------------------------------------------------------------------------
__global__ __launch_bounds__(512) void dcn_sample(
    const unsigned short* __restrict__ vbf,    // [n][4096][256] bf16
    const unsigned short* __restrict__ ombf,   // [m][432] bf16
    unsigned short* __restrict__ sampled)      // [m][256] bf16
{
    __shared__ unsigned short v_s[144 * 128];  // 36864 B
    __shared__ unsigned short om_s[64 * 216];  // 27648 B
    const int t = threadIdx.x;
    const int b = blockIdx.x;
    const int chalf = b & 1;
    const int tile  = b >> 1;
    const int n   = tile >> 6;
    const int py0 = ((tile >> 3) & 7) * 8;
    const int px0 = (tile & 7) * 8;
    const int y0t = py0 - 2, x0t = px0 - 2;

    {   // stage v half-tile: 144 slots x 128ch = 2304 uint4
        uint4* vd = (uint4*)v_s;
        const unsigned short* vn = vbf + ((size_t)n << 12) * 256 + chalf * 128;
        for (int j = t; j < 2304; j += 512) {
            const int slot = j >> 4, wi = j & 15;
            const int ly = slot / 12, lx = slot - ly * 12;
            const int gy = min(max(y0t + ly, 0), 63);
            const int gx = min(max(x0t + lx, 0), 63);
            vd[j] = *(const uint4*)(vn + (size_t)((gy << 6) + gx) * 256 + wi * 8);
        }
        // stage om half: 64 px x 216 bf16 = 1728 uint4
        uint4* od = (uint4*)om_s;
        for (int j = t; j < 1728; j += 512) {
            const int pl = j / 27, wi = j - pl * 27;
            const int m = (n << 12) + ((py0 + (pl >> 3)) << 6) + px0 + (pl & 7);
            od[j] = *(const uint4*)(ombf + (size_t)m * OMC + chalf * 216 + wi * 8);
        }
    }
    __syncthreads();

    const int lane  = t & 63;
    const int wv    = t >> 6;            // wave id 0..7
    const int pxsel = lane >> 5;         // 0..1
    const int g     = (lane >> 2) & 7;   // local group 0..7
    const int cl    = lane & 3;
    const int chl   = g * 16 + cl * 4;   // local channel 0..127

#pragma unroll 1
    for (int i = 0; i < 4; i++) {
        const int pl = wv * 8 + i * 2 + pxsel;
        const int h  = py0 + (pl >> 3);
        const int w  = px0 + (pl & 7);
        const unsigned short* omr = om_s + pl * 216 + g * 27;
        float4 acc = make_float4(0.f, 0.f, 0.f, 0.f);
#pragma unroll
        for (int k = 0; k < 9; k++) {
            const float offy = bf2f(omr[2 * k]);
            const float offx = bf2f(omr[2 * k + 1]);
            const float mk   = bf2f(omr[18 + k]);
            const float sy = (float)(h + k / 3 - 1) + offy;
            const float sx = (float)(w + k % 3 - 1) + offx;
            const float y0f = floorf(sy), x0f = floorf(sx);
            const float fy = sy - y0f, fx = sx - x0f;
            const int y0 = (int)y0f, x0 = (int)x0f;
            const float ay  = ((unsigned)y0 < 64u) ? (1.f - fy) : 0.f;
            const float by  = ((unsigned)(y0 + 1) < 64u) ? fy : 0.f;
            const float axm = (((unsigned)x0 < 64u) ? (1.f - fx) : 0.f) * mk;
            const float bxm = (((unsigned)(x0 + 1) < 64u) ? fx : 0.f) * mk;
            const float w00 = ay * axm, w01 = ay * bxm;
            const float w10 = by * axm, w11 = by * bxm;
            const int ly = y0 - y0t, lx = x0 - x0t;
            if ((unsigned)ly <= 10u && (unsigned)lx <= 10u) {
                const unsigned short* p00 = v_s + ((ly * 12 + lx) * 128 + chl);
                acc4(p00,                  w00, acc);
                acc4(p00 + 128,            w01, acc);
                acc4(p00 + 12 * 128,       w10, acc);
                acc4(p00 + 12 * 128 + 128, w11, acc);
            } else {
                const int yc0 = min(max(y0, 0), 63), yc1 = min(max(y0 + 1, 0), 63);
                const int xc0 = min(max(x0, 0), 63), xc1 = min(max(x0 + 1, 0), 63);
                const unsigned short* vg =
                    vbf + ((size_t)n << 12) * 256 + chalf * 128 + chl;
                acc4(vg + (size_t)((yc0 << 6) + xc0) * 256, w00, acc);
                acc4(vg + (size_t)((yc0 << 6) + xc1) * 256, w01, acc);
                acc4(vg + (size_t)((yc1 << 6) + xc0) * 256, w10, acc);
                acc4(vg + (size_t)((yc1 << 6) + xc1) * 256, w11, acc);
            }
        }
        const int m = (n << 12) + (h << 6) + w;
        const unsigned lo = (unsigned)f2bf(acc.x) | ((unsigned)f2bf(acc.y) << 16);
        const unsigned hi = (unsigned)f2bf(acc.z) | ((unsigned)f2bf(acc.w) << 16);
        *reinterpret_cast<uint2*>(sampled + (size_t)m * 256 + chalf * 128 + chl)
            = make_uint2(lo, hi);
    }
}

// ---------------------------------------------------------------------------
// Output GEMM + fused per-block channel stats. o stored bf16; stats from fp32.
// 128x128 tile, BK=32, 4 waves (2x2). XCD-swizzled (2 col-tiles same XCD).
// ---------------------------------------------------------------------------
__global__ __launch_bounds__(256) void gemm_out(
    const unsigned short* __restrict__ A,
    const unsigned short* __restrict__ Bt,
    const float* __restrict__ bias,
    unsigned short* __restrict__ obf,
    float* __restrict__ psum, float* __restrict__ psumsq)
{
    __shared__ unsigned short As[128 * 32];
    __shared__ unsigned short Bs[128 * 32];
    __shared__ float ssum[2][128];
    __shared__ float sqsum[2][128];
    const int t    = threadIdx.x;
    const int lane = t & 63;
    const int wr   = (t >> 7);
    const int wc   = (t >> 6) & 1;
    const int vid = blockIdx.x + 2 * blockIdx.y;
    const int xcd = vid & 7;
    const int j8  = vid >> 3;             // 0..31
    const int by   = xcd * 16 + (j8 >> 1);
    const int row0 = by * 128;
    const int col0 = (j8 & 1) * 128;

    f32x4 acc[4][4];
#pragma unroll
    for (int m = 0; m < 4; m++)
#pragma unroll
        for (int n = 0; n < 4; n++) acc[m][n] = (f32x4)0.f;

    const int r0   = t >> 2;
    const int koff = (t & 3) * 8;
    const unsigned short* gA = A  + (size_t)(row0 + r0) * 256 + koff;
    const unsigned short* gB = Bt + (size_t)(col0 + r0) * 256 + koff;
    const int wbase = (t & 192) * 8;

    const int aoff = ((wr * 64) + (lane & 15)) * 32 + (lane >> 4) * 8;
    const int boff = ((wc * 64) + (lane & 15)) * 32 + (lane >> 4) * 8;

    for (int k0 = 0; k0 < 256; k0 += 32) {
        gload16(gA + k0,            As + wbase);
        gload16(gA + k0 + 64 * 256, As + 2048 + wbase);
        gload16(gB + k0,            Bs + wbase);
        gload16(gB + k0 + 64 * 256, Bs + 2048 + wbase);
        __syncthreads();

        short8v a_[4], b_[4];
#pragma unroll
        for (int m = 0; m < 4; m++)
            a_[m] = *(const short8v*)(As + aoff + m * 16 * 32);
#pragma unroll
        for (int n = 0; n < 4; n++)
            b_[n] = *(const short8v*)(Bs + boff + n * 16 * 32);
#pragma unroll
        for (int m = 0; m < 4; m++)
#pragma unroll
            for (int n = 0; n < 4; n++)
                acc[m][n] = __builtin_amdgcn_mfma_f32_16x16x32_bf16(
                    a_[m], b_[n], acc[m][n], 0, 0, 0);
        __syncthreads();
    }

    const int rbase = row0 + wr * 64 + ((lane >> 4) << 2);
    const int cloc  = wc * 64 + (lane & 15);
#pragma unroll
    for (int n = 0; n < 4; n++) {
        const int col = col0 + cloc + n * 16;
        const float bb = bias[col];
        float s = 0.f, q = 0.f;
#pragma unroll
        for (int m = 0; m < 4; m++) {
#pragma unroll
            for (int r = 0; r < 4; r++) {
                const float val = acc[m][n][r] + bb;
                obf[(size_t)(rbase + m * 16 + r) * C2c + col] = f2bf(val);
                s += val; q += val * val;
            }
        }
        s += __shfl_xor(s, 16); s += __shfl_xor(s, 32);
        q += __shfl_xor(q, 16); q += __shfl_xor(q, 32);
        if (lane < 16) {
            ssum[wr][cloc + n * 16]  = s;
            sqsum[wr][cloc + n * 16] = q;
        }
    }
    __syncthreads();
    if (t < 128) {
        psum[(size_t)by * 256 + col0 + t]   = ssum[0][t] + ssum[1][t];
        psumsq[(size_t)by * 256 + col0 + t] = sqsum[0][t] + sqsum[1][t];
    }
}

__global__ __launch_bounds__(256) void stats2(
    const float* __restrict__ psum, const float* __restrict__ psumsq,
    float* __restrict__ meanp, float* __restrict__ rsigp)
{
    const int t = threadIdx.x;
    float s0 = 0.f, s1 = 0.f, s2_ = 0.f, s3 = 0.f;
    float q0 = 0.f, q1 = 0.f, q2 = 0.f, q3 = 0.f;
    for (int b = 0; b < 128; b += 4) {
        s0  += psum[(b + 0) * 256 + t];   q0 += psumsq[(b + 0) * 256 + t];
        s1  += psum[(b + 1) * 256 + t];   q1 += psumsq[(b + 1) * 256 + t];
        s2_ += psum[(b + 2) * 256 + t];   q2 += psumsq[(b + 2) * 256 + t];
        s3  += psum[(b + 3) * 256 + t];   q3 += psumsq[(b + 3) * 256 + t];
    }
    const float s = (s0 + s1) + (s2_ + s3);
    const float q = (q0 + q1) + (q2 + q3);
    const float inv = 1.f / (float)Mrows;
    const float mean = s * inv;
    const float var  = q * inv - mean * mean;
    meanp[t] = mean;
    rsigp[t] = rsqrtf(var + EPSc);
}

// ---------------------------------------------------------------------------
// Normalize + SiLU + NHWC->NCHW transpose. o is bf16. 64px x 64ch per block.
// ---------------------------------------------------------------------------
__global__ __launch_bounds__(256) void norm_silu_transpose(
    const unsigned short* __restrict__ obf, const float* __restrict__ meanp,
    const float* __restrict__ rsigp, const float* __restrict__ gamma,
    const float* __restrict__ beta, float* __restrict__ out)
{
    __shared__ float tile[64][65];
    const int tid = threadIdx.x;
    const int p0 = blockIdx.x * 64;
    const int c0 = blockIdx.y * 64;
    const int n  = blockIdx.z;
    const int m0 = n * HWc + p0;
    {
#pragma unroll
        for (int i = 0; i < 8; i++) {
            const int idx = i * 256 + tid;
            const int p  = idx >> 5;
            const int cp = (idx & 31) * 2;
            const unsigned u = *reinterpret_cast<const unsigned*>(
                obf + (size_t)(m0 + p) * C2c + c0 + cp);
            tile[p][cp]     = __builtin_bit_cast(float, u << 16);
            tile[p][cp + 1] = __builtin_bit_cast(float, u & 0xffff0000u);
        }
    }
    __syncthreads();
    {
        const int lp = tid & 63, lcq = tid >> 6;
#pragma unroll
        for (int i = 0; i < 16; i++) {
            const int c  = lcq * 16 + i;
            const int ch = c0 + c;
            const float x = tile[lp][c];
            const float y = gamma[ch] * (x - meanp[ch]) * rsigp[ch] + beta[ch];
            const float sy = y / (1.f + expf(-y));
            out[(size_t)n * C2c * HWc + (size_t)ch * HWc + p0 + lp] = sy;
        }
    }
}

// ---------------------------------------------------------------------------
extern "C" void kernel_launch(void* const* d_in, const int* in_sizes, int n_in,
                              void* d_out, int out_size, void* d_ws, size_t ws_size,
                              hipStream_t stream)
{
    const float* x     = (const float*)d_in[0];
    const float* Wv    = (const float*)d_in[1];
    const float* bv    = (const float*)d_in[2];
    const float* Wom   = (const float*)d_in[3];
    const float* bom   = (const float*)d_in[4];
    const float* Wout  = (const float*)d_in[5];
    const float* bout  = (const float*)d_in[6];
    const float* gamma = (const float*)d_in[7];
    const float* beta  = (const float*)d_in[8];
    float* out = (float*)d_out;

    unsigned short* us = (unsigned short*)d_ws;
    unsigned short* Ax    = us;                    // 4,194,304
    unsigned short* vbf   = Ax + 4194304;          // 4,194,304
    unsigned short* ombf  = vbf + 4194304;         // 7,077,888
    unsigned short* samp  = ombf + 7077888;        // 4,194,304
    unsigned short* obf   = samp + 4194304;        // 4,194,304
    unsigned short* WallT = obf + 4194304;         // 196,608
    unsigned short* WoutT = WallT + 196608;        // 65,536
    float* fs     = (float*)(WoutT + 65536);
    float* psum   = fs;                            // 32,768
    float* psumsq = psum + 32768;                  // 32,768
    float* meanp  = psumsq + 32768;
    float* rsigp  = meanp + 256;
    float* ball   = rsigp + 256;                   // 768

    // fused conversions (x transpose + weights)
    prep<<<2051, 256, 0, stream>>>(x, Wv, Wom, Wout, bv, bom,
                                   Ax, WallT, WoutT, ball);
    // v (cols 0..255) + om (cols 256..687) in one GEMM, XCD-swizzled
    gemm_vom<<<dim3(3, 128), 512, 0, stream>>>(Ax, WallT, ball, vbf, ombf);
    // deformable sampling (LDS-tiled, channel-split, 2 blocks/CU) -> bf16
    dcn_sample<<<512, 512, 0, stream>>>(vbf, ombf, samp);
    // o = sampled @ Wout + bout -> bf16, with fused per-block channel stats
    gemm_out<<<dim3(2, 128), 256, 0, stream>>>(samp, WoutT, bout, obf, psum, psumsq);
    stats2<<<1, 256, 0, stream>>>(psum, psumsq, meanp, rsigp);
    norm_silu_transpose<<<dim3(64, 4, 4), 256, 0, stream>>>(obf, meanp, rsigp,
                                                            gamma, beta, out);
}